// Round 3
// baseline (1566.926 us; speedup 1.0000x reference)
//
#include <hip/hip_runtime.h>

constexpr int N_NODES = 50000;
constexpr int N_EDGES = 800000;
constexpr int ND  = 32;
constexpr int ED  = 16;
constexpr int HID = 96;
constexpr int NLAYER = 3;

typedef unsigned short ushort_t;
typedef unsigned int uint_t;
typedef __attribute__((ext_vector_type(8))) short bf16x8;
typedef __attribute__((ext_vector_type(4))) float f32x4;

__device__ __forceinline__ float bf2f(ushort_t u) {
    union { float f; uint_t ui; } c; c.ui = ((uint_t)u) << 16; return c.f;
}
__device__ __forceinline__ ushort_t f2bf(float f) {
    uint_t u = __float_as_uint(f);
    return (ushort_t)((u + 0x7FFFu + ((u >> 16) & 1u)) >> 16);  // RNE
}

// ---------------- CSR build (by dst), once per call ----------------
__global__ void k_count_deg(const int* __restrict__ dst, int* __restrict__ deg) {
    int e4 = blockIdx.x * 256 + threadIdx.x;
    if (e4 * 4 >= N_EDGES) return;
    int4 d = ((const int4*)dst)[e4];
    atomicAdd(&deg[d.x], 1); atomicAdd(&deg[d.y], 1);
    atomicAdd(&deg[d.z], 1); atomicAdd(&deg[d.w], 1);
}

__global__ void k_scan_block(const int* __restrict__ deg, int* __restrict__ rowptr,
                             int* __restrict__ bsum) {
    __shared__ int s[256];
    int i = blockIdx.x * 256 + threadIdx.x;
    int v = (i < N_NODES) ? deg[i] : 0;
    s[threadIdx.x] = v;
    __syncthreads();
    for (int off = 1; off < 256; off <<= 1) {
        int t = (threadIdx.x >= off) ? s[threadIdx.x - off] : 0;
        __syncthreads();
        s[threadIdx.x] += t;
        __syncthreads();
    }
    if (i < N_NODES) rowptr[i] = s[threadIdx.x] - v;
    if (threadIdx.x == 255) bsum[blockIdx.x] = s[255];
}

__global__ void k_scan_bsum(int* __restrict__ bsum, int nb) {
    __shared__ int s[256];
    int t = threadIdx.x;
    int v = (t < nb) ? bsum[t] : 0;
    s[t] = v;
    __syncthreads();
    for (int off = 1; off < 256; off <<= 1) {
        int tv = (t >= off) ? s[t - off] : 0;
        __syncthreads();
        s[t] += tv;
        __syncthreads();
    }
    if (t < nb) bsum[t] = s[t] - v;
}

__global__ void k_scan_add(int* __restrict__ rowptr, const int* __restrict__ bsum) {
    int i = blockIdx.x * 256 + threadIdx.x;
    if (i < N_NODES) rowptr[i] += bsum[blockIdx.x];
    if (i == 0) rowptr[N_NODES] = N_EDGES;
}

__global__ void k_scatter(const int* __restrict__ src, const int* __restrict__ dst,
                          const int* __restrict__ rowptr, int* __restrict__ fill,
                          int* __restrict__ srcs, int* __restrict__ eidxp,
                          int* __restrict__ pdst) {
    int e4 = blockIdx.x * 256 + threadIdx.x;
    if (e4 * 4 >= N_EDGES) return;
    int4 s = ((const int4*)src)[e4];
    int4 d = ((const int4*)dst)[e4];
    int e0 = e4 * 4;
    int p0 = rowptr[d.x] + atomicAdd(&fill[d.x], 1);
    srcs[p0] = s.x; eidxp[p0] = e0;     pdst[p0] = d.x;
    int p1 = rowptr[d.y] + atomicAdd(&fill[d.y], 1);
    srcs[p1] = s.y; eidxp[p1] = e0 + 1; pdst[p1] = d.y;
    int p2 = rowptr[d.z] + atomicAdd(&fill[d.z], 1);
    srcs[p2] = s.z; eidxp[p2] = e0 + 2; pdst[p2] = d.z;
    int p3 = rowptr[d.w] + atomicAdd(&fill[d.w], 1);
    srcs[p3] = s.w; eidxp[p3] = e0 + 3; pdst[p3] = d.w;
}

// ---- permute eattr into CSR order, fp32 -> bf16 (layer-invariant, once) ----
__global__ void k_perm(const int* __restrict__ eidxp, const float* __restrict__ eattr,
                       ushort_t* __restrict__ ea) {
    int tid = blockIdx.x * 256 + threadIdx.x;
    int p = tid >> 2, q = tid & 3;
    if (p >= N_EDGES) return;
    int e = eidxp[p];
    float4 v = *(const float4*)(eattr + (size_t)e * ED + q * 4);
    uint_t lo = (uint_t)f2bf(v.x) | ((uint_t)f2bf(v.y) << 16);
    uint_t hi = (uint_t)f2bf(v.z) | ((uint_t)f2bf(v.w) << 16);
    *(uint2*)(ea + (size_t)p * ED + q * 4) = make_uint2(lo, hi);
}

// ---------------- proj: h = x @ proj_w + proj_b  (K=32) ----------------
__global__ __launch_bounds__(192) void k_proj(const float* __restrict__ x,
                                              const float* __restrict__ pw,
                                              const float* __restrict__ pb,
                                              float* __restrict__ h) {
    int t = threadIdx.x;
    int c = t % 96, half = t / 96;
    float wreg[ND];
#pragma unroll
    for (int k = 0; k < ND; k++) wreg[k] = pw[k * HID + c];
    float b = pb[c];
    int n0 = blockIdx.x * 16 + half * 8;
    for (int i = 0; i < 8; i += 2) {
        int na = n0 + i, nb = na + 1;
        const float4* xa = (const float4*)(x + (size_t)na * ND);
        const float4* xb = (const float4*)(x + (size_t)nb * ND);
        float accA = b, accB = b;
#pragma unroll
        for (int k4 = 0; k4 < ND / 4; k4++) {
            float4 va = xa[k4], vb = xb[k4];
            accA += va.x * wreg[4 * k4] + va.y * wreg[4 * k4 + 1] +
                    va.z * wreg[4 * k4 + 2] + va.w * wreg[4 * k4 + 3];
            accB += vb.x * wreg[4 * k4] + vb.y * wreg[4 * k4 + 1] +
                    vb.z * wreg[4 * k4 + 2] + vb.w * wreg[4 * k4 + 3];
        }
        h[(size_t)na * HID + c] = accA;
        h[(size_t)nb * HID + c] = accB;
    }
}

// ---- xl = h@Wl+bl, xr = h@Wr+br; both bf16 out; fused, K=96 ----
__global__ __launch_bounds__(192) void k_lin_lr(const float* __restrict__ h,
                                                const float* __restrict__ Wl,
                                                const float* __restrict__ bl,
                                                const float* __restrict__ Wr,
                                                const float* __restrict__ br,
                                                ushort_t* __restrict__ xl,
                                                ushort_t* __restrict__ xr) {
    int t = threadIdx.x;
    int c = t % 96, half = t / 96;
    const float* W = half ? Wr : Wl;
    float b = half ? br[c] : bl[c];
    ushort_t* out = half ? xr : xl;
    float wreg[HID];
#pragma unroll
    for (int k = 0; k < HID; k++) wreg[k] = W[k * HID + c];
    int n0 = blockIdx.x * 16;
    for (int i = 0; i < 16; i += 2) {
        int na = n0 + i, nb = na + 1;
        const float4* ha = (const float4*)(h + (size_t)na * HID);
        const float4* hb = (const float4*)(h + (size_t)nb * HID);
        float accA = b, accB = b;
#pragma unroll
        for (int k4 = 0; k4 < HID / 4; k4++) {
            float4 va = ha[k4], vb = hb[k4];
            accA += va.x * wreg[4 * k4] + va.y * wreg[4 * k4 + 1] +
                    va.z * wreg[4 * k4 + 2] + va.w * wreg[4 * k4 + 3];
            accB += vb.x * wreg[4 * k4] + vb.y * wreg[4 * k4 + 1] +
                    vb.z * wreg[4 * k4 + 2] + vb.w * wreg[4 * k4 + 3];
        }
        out[(size_t)na * HID + c] = f2bf(accA);
        out[(size_t)nb * HID + c] = f2bf(accB);
    }
}

// ---- k_ev: edge-parallel attention weights via MFMA ----
// Wave handles 8 batches of 16 CSR positions. D = We^T[96,32] @ ea^T[32,16]
// (K=16 zero-padded to 32). D layout: col=lane&15=position, row=quad*4+reg=
// channel-in-16-chunk. z = xl[src]+xr[dst]+e, leakyrelu, per-head att-dot via
// U/V quad shuffle sums (head boundaries at 24 = chunk-and-a-half).
__global__ __launch_bounds__(256) void k_ev(
    const ushort_t* __restrict__ xlb, const ushort_t* __restrict__ xrb,
    const ushort_t* __restrict__ ea, const int* __restrict__ srcs,
    const int* __restrict__ pdst, const float* __restrict__ WeL,
    const float* __restrict__ attL, float4* __restrict__ ev) {
    int wid = blockIdx.x * 4 + (threadIdx.x >> 6);
    int lane = threadIdx.x & 63;
    int col = lane & 15, quad = lane >> 4;

    // wave-invariant A fragments (We^T) and att values
    bf16x8 afr[6];
#pragma unroll
    for (int mc = 0; mc < 6; mc++) {
        bf16x8 a = {0, 0, 0, 0, 0, 0, 0, 0};
        if (quad < 2) {
#pragma unroll
            for (int j = 0; j < 8; j++)
                a[j] = (short)f2bf(WeL[(quad * 8 + j) * HID + mc * 16 + col]);
        }
        afr[mc] = a;
    }
    float attr[6][4];
#pragma unroll
    for (int mc = 0; mc < 6; mc++)
#pragma unroll
        for (int r = 0; r < 4; r++)
            attr[mc][r] = attL[mc * 16 + quad * 4 + r];

#pragma unroll 2
    for (int b = 0; b < 8; b++) {
        int p0 = wid * 128 + b * 16;
        if (p0 >= N_EDGES) continue;
        int p = p0 + col;
        bf16x8 bfr = {0, 0, 0, 0, 0, 0, 0, 0};
        if (quad < 2)
            bfr = *(const bf16x8*)(ea + (size_t)p * ED + quad * 8);
        f32x4 zero4 = {0.f, 0.f, 0.f, 0.f};
        f32x4 d[6];
#pragma unroll
        for (int mc = 0; mc < 6; mc++)
            d[mc] = __builtin_amdgcn_mfma_f32_16x16x32_bf16(afr[mc], bfr, zero4, 0, 0, 0);

        int src = srcs[p], dst = pdst[p];
        float s[6];
#pragma unroll
        for (int mc = 0; mc < 6; mc++) {
            int cb = mc * 16 + quad * 4;
            uint2 xu = *(const uint2*)(xlb + (size_t)src * HID + cb);
            uint2 ru = *(const uint2*)(xrb + (size_t)dst * HID + cb);
            float x0 = bf2f((ushort_t)(xu.x & 0xffff)), x1 = bf2f((ushort_t)(xu.x >> 16));
            float x2 = bf2f((ushort_t)(xu.y & 0xffff)), x3 = bf2f((ushort_t)(xu.y >> 16));
            float r0 = bf2f((ushort_t)(ru.x & 0xffff)), r1 = bf2f((ushort_t)(ru.x >> 16));
            float r2 = bf2f((ushort_t)(ru.y & 0xffff)), r3 = bf2f((ushort_t)(ru.y >> 16));
            float z0 = x0 + r0 + d[mc][0]; z0 = z0 > 0.f ? z0 : 0.2f * z0;
            float z1 = x1 + r1 + d[mc][1]; z1 = z1 > 0.f ? z1 : 0.2f * z1;
            float z2 = x2 + r2 + d[mc][2]; z2 = z2 > 0.f ? z2 : 0.2f * z2;
            float z3 = x3 + r3 + d[mc][3]; z3 = z3 > 0.f ? z3 : 0.2f * z3;
            s[mc] = z0 * attr[mc][0] + z1 * attr[mc][1] +
                    z2 * attr[mc][2] + z3 * attr[mc][3];
        }
        float U[6], V[6];
#pragma unroll
        for (int mc = 0; mc < 6; mc++) {
            U[mc] = s[mc] + __shfl_xor(s[mc], 16);
            V[mc] = U[mc] + __shfl_xor(U[mc], 32);
        }
        if (quad == 0) {
            float h0 = V[0] + U[1];
            float h1 = (V[1] - U[1]) + V[2];
            float h2 = V[3] + U[4];
            float h3 = (V[4] - U[4]) + V[5];
            ev[p] = make_float4(__expf(h0), __expf(h1), __expf(h2), __expf(h3));
        }
    }
}

// ---- k_agg: weighted sum + residual + LayerNorm. Wave per node,
// 4 edge slots x 16 channel-lanes (6 ch each), software-pipelined. ----
__global__ __launch_bounds__(256) void k_agg(
    const ushort_t* __restrict__ xlb, const float* __restrict__ evf,
    const int* __restrict__ srcs, const int* __restrict__ rowptr,
    const float* __restrict__ convb, const float* __restrict__ lng,
    const float* __restrict__ lnb, float* __restrict__ h) {
    int lane = threadIdx.x & 63;
    int node = blockIdx.x * 4 + (threadIdx.x >> 6);
    int slot = lane >> 4, q = lane & 15;
    int c0 = q * 6, head = q >> 2;
    int beg = rowptr[node], end = rowptr[node + 1];
    int cnt = (end - beg + 3) >> 2;

    float n0 = 0.f, n1 = 0.f, n2 = 0.f, n3 = 0.f, n4 = 0.f, n5 = 0.f, den = 0.f;
    if (cnt > 0) {
        int p = beg + slot;
        bool v = p < end;
        int pc = v ? p : beg;
        int src = srcs[pc];
        float evv = evf[4 * pc + head];
        const ushort_t* xp = xlb + (size_t)src * HID + c0;
        uint_t a0 = *(const uint_t*)(xp);
        uint_t a1 = *(const uint_t*)(xp + 2);
        uint_t a2 = *(const uint_t*)(xp + 4);
        for (int it = 0; it < cnt; ++it) {
            int pn = beg + (it + 1) * 4 + slot;
            bool vn = pn < end;
            int pcn = vn ? pn : beg;
            int srcn = srcs[pcn];
            float evn = evf[4 * pcn + head];
            const ushort_t* xpn = xlb + (size_t)srcn * HID + c0;
            uint_t b0 = *(const uint_t*)(xpn);
            uint_t b1 = *(const uint_t*)(xpn + 2);
            uint_t b2 = *(const uint_t*)(xpn + 4);

            float e = v ? evv : 0.f;
            n0 += e * bf2f((ushort_t)(a0 & 0xffff));
            n1 += e * bf2f((ushort_t)(a0 >> 16));
            n2 += e * bf2f((ushort_t)(a1 & 0xffff));
            n3 += e * bf2f((ushort_t)(a1 >> 16));
            n4 += e * bf2f((ushort_t)(a2 & 0xffff));
            n5 += e * bf2f((ushort_t)(a2 >> 16));
            den += e;

            v = vn; evv = evn; a0 = b0; a1 = b1; a2 = b2;
        }
    }
    // combine 4 slots
    n0 += __shfl_xor(n0, 16); n0 += __shfl_xor(n0, 32);
    n1 += __shfl_xor(n1, 16); n1 += __shfl_xor(n1, 32);
    n2 += __shfl_xor(n2, 16); n2 += __shfl_xor(n2, 32);
    n3 += __shfl_xor(n3, 16); n3 += __shfl_xor(n3, 32);
    n4 += __shfl_xor(n4, 16); n4 += __shfl_xor(n4, 32);
    n5 += __shfl_xor(n5, 16); n5 += __shfl_xor(n5, 32);
    den += __shfl_xor(den, 16); den += __shfl_xor(den, 32);

    size_t nb = (size_t)node * HID + c0;
    float inv = 1.f / (den + 1e-16f);
    float v0 = h[nb + 0] + n0 * inv + convb[c0 + 0];
    float v1 = h[nb + 1] + n1 * inv + convb[c0 + 1];
    float v2 = h[nb + 2] + n2 * inv + convb[c0 + 2];
    float v3 = h[nb + 3] + n3 * inv + convb[c0 + 3];
    float v4 = h[nb + 4] + n4 * inv + convb[c0 + 4];
    float v5 = h[nb + 5] + n5 * inv + convb[c0 + 5];
    float sm = v0 + v1 + v2 + v3 + v4 + v5;
    sm += __shfl_xor(sm, 1); sm += __shfl_xor(sm, 2);
    sm += __shfl_xor(sm, 4); sm += __shfl_xor(sm, 8);
    float mu = sm * (1.f / 96.f);
    float d0 = v0 - mu, d1 = v1 - mu, d2 = v2 - mu;
    float d3 = v3 - mu, d4 = v4 - mu, d5 = v5 - mu;
    float sv = d0 * d0 + d1 * d1 + d2 * d2 + d3 * d3 + d4 * d4 + d5 * d5;
    sv += __shfl_xor(sv, 1); sv += __shfl_xor(sv, 2);
    sv += __shfl_xor(sv, 4); sv += __shfl_xor(sv, 8);
    float rstd = rsqrtf(sv * (1.f / 96.f) + 1e-5f);
    if (slot == 0) {
        h[nb + 0] = d0 * rstd * lng[c0 + 0] + lnb[c0 + 0];
        h[nb + 1] = d1 * rstd * lng[c0 + 1] + lnb[c0 + 1];
        h[nb + 2] = d2 * rstd * lng[c0 + 2] + lnb[c0 + 2];
        h[nb + 3] = d3 * rstd * lng[c0 + 3] + lnb[c0 + 3];
        h[nb + 4] = d4 * rstd * lng[c0 + 4] + lnb[c0 + 4];
        h[nb + 5] = d5 * rstd * lng[c0 + 5] + lnb[c0 + 5];
    }
}

// ---------------- head: gelu(h@W1+b1)@W2+b2, 4 threads per node ----------------
__global__ __launch_bounds__(256) void k_head(const float* __restrict__ h,
                                              const float* __restrict__ W1,
                                              const float* __restrict__ b1,
                                              const float* __restrict__ W2,
                                              const float* __restrict__ b2,
                                              float* __restrict__ out) {
    int gid = blockIdx.x * 256 + threadIdx.x;
    int n = gid >> 2, q = gid & 3;
    if (n >= N_NODES) return;
    float hr[HID];
    const float4* h4 = (const float4*)(h + (size_t)n * HID);
#pragma unroll
    for (int i = 0; i < HID / 4; i++) {
        float4 v = h4[i];
        hr[4 * i] = v.x; hr[4 * i + 1] = v.y; hr[4 * i + 2] = v.z; hr[4 * i + 3] = v.w;
    }
    const float inv_sqrt2 = 0.70710678118654752f;
    float y = 0.f;
    int j0 = q * 12;
    for (int g = 0; g < 3; g++) {
        int j = j0 + 4 * g;
        float4 acc = make_float4(b1[j], b1[j + 1], b1[j + 2], b1[j + 3]);
#pragma unroll
        for (int k = 0; k < HID; k++) {
            float4 w = *(const float4*)(W1 + k * 48 + j);
            acc.x += hr[k] * w.x; acc.y += hr[k] * w.y;
            acc.z += hr[k] * w.z; acc.w += hr[k] * w.w;
        }
        float g0 = 0.5f * acc.x * (1.f + erff(acc.x * inv_sqrt2));
        float g1 = 0.5f * acc.y * (1.f + erff(acc.y * inv_sqrt2));
        float g2 = 0.5f * acc.z * (1.f + erff(acc.z * inv_sqrt2));
        float g3 = 0.5f * acc.w * (1.f + erff(acc.w * inv_sqrt2));
        y += g0 * W2[j] + g1 * W2[j + 1] + g2 * W2[j + 2] + g3 * W2[j + 3];
    }
    y += __shfl_xor(y, 1);
    y += __shfl_xor(y, 2);
    if (q == 0) out[n] = y + b2[0];
}

extern "C" void kernel_launch(void* const* d_in, const int* in_sizes, int n_in,
                              void* d_out, int out_size, void* d_ws, size_t ws_size,
                              hipStream_t stream) {
    const float* x       = (const float*)d_in[0];
    const int*   eidx    = (const int*)  d_in[1];
    const float* eattr   = (const float*)d_in[2];
    const float* proj_w  = (const float*)d_in[3];
    const float* proj_b  = (const float*)d_in[4];
    const float* lin_l_w = (const float*)d_in[5];
    const float* lin_l_b = (const float*)d_in[6];
    const float* lin_r_w = (const float*)d_in[7];
    const float* lin_r_b = (const float*)d_in[8];
    const float* lin_e_w = (const float*)d_in[9];
    const float* att     = (const float*)d_in[10];
    const float* conv_b  = (const float*)d_in[11];
    const float* ln_g    = (const float*)d_in[12];
    const float* ln_b    = (const float*)d_in[13];
    const float* head_w1 = (const float*)d_in[14];
    const float* head_b1 = (const float*)d_in[15];
    const float* head_w2 = (const float*)d_in[16];
    const float* head_b2 = (const float*)d_in[17];
    float* out = (float*)d_out;

    char* p = (char*)d_ws;
    auto alloc = [&](size_t bytes) -> char* {
        char* r = p;
        p += (bytes + 255) & ~size_t(255);
        return r;
    };
    float*    h      = (float*)alloc(sizeof(float) * (size_t)N_NODES * HID);
    ushort_t* xl     = (ushort_t*)alloc(2 * (size_t)N_NODES * HID);
    ushort_t* xr     = (ushort_t*)alloc(2 * (size_t)N_NODES * HID);
    int*      deg    = (int*)alloc(4 * (size_t)N_NODES);
    int*      fill   = (int*)alloc(4 * (size_t)N_NODES);
    int*      rowptr = (int*)alloc(4 * (size_t)(N_NODES + 1));
    int*      bsum   = (int*)alloc(4 * 256);
    int*      srcs   = (int*)alloc(4 * (size_t)N_EDGES);
    int*      eidxp  = (int*)alloc(4 * (size_t)N_EDGES);
    int*      pdst   = (int*)alloc(4 * (size_t)N_EDGES);
    ushort_t* ea_csr = (ushort_t*)alloc(2 * (size_t)N_EDGES * ED);
    float4*   ev     = (float4*)alloc(16 * (size_t)N_EDGES);

    const int* srcA = eidx;
    const int* dstA = eidx + N_EDGES;

    int ebl4 = (N_EDGES / 4 + 255) / 256;  // 782
    int nbl  = (N_NODES + 255) / 256;      // 196

    hipMemsetAsync(deg, 0, 4 * (size_t)N_NODES, stream);
    hipMemsetAsync(fill, 0, 4 * (size_t)N_NODES, stream);
    k_count_deg<<<ebl4, 256, 0, stream>>>(dstA, deg);
    k_scan_block<<<nbl, 256, 0, stream>>>(deg, rowptr, bsum);
    k_scan_bsum<<<1, 256, 0, stream>>>(bsum, nbl);
    k_scan_add<<<nbl, 256, 0, stream>>>(rowptr, bsum);
    k_scatter<<<ebl4, 256, 0, stream>>>(srcA, dstA, rowptr, fill, srcs, eidxp, pdst);
    k_perm<<<(N_EDGES * 4) / 256, 256, 0, stream>>>(eidxp, eattr, ea_csr);

    k_proj<<<N_NODES / 16, 192, 0, stream>>>(x, proj_w, proj_b, h);
    for (int l = 0; l < NLAYER; l++) {
        k_lin_lr<<<N_NODES / 16, 192, 0, stream>>>(
            h, lin_l_w + (size_t)l * HID * HID, lin_l_b + (size_t)l * HID,
            lin_r_w + (size_t)l * HID * HID, lin_r_b + (size_t)l * HID, xl, xr);
        k_ev<<<1563, 256, 0, stream>>>(xl, xr, ea_csr, srcs, pdst,
                                       lin_e_w + (size_t)l * ED * HID,
                                       att + (size_t)l * HID,
                                       (float4*)ev);
        k_agg<<<N_NODES / 4, 256, 0, stream>>>(
            xl, (const float*)ev, srcs, rowptr, conv_b + (size_t)l * HID,
            ln_g + (size_t)l * HID, ln_b + (size_t)l * HID, h);
    }
    k_head<<<(N_NODES * 4 + 255) / 256, 256, 0, stream>>>(h, head_w1, head_b1,
                                                          head_w2, head_b2, out);
}

// Round 4
// 674.952 us; speedup vs baseline: 2.3215x; 2.3215x over previous
//
#include <hip/hip_runtime.h>

constexpr int N_NODES = 50000;
constexpr int N_EDGES = 800000;
constexpr int ND  = 32;
constexpr int ED  = 16;
constexpr int HID = 96;
constexpr int NLAYER = 3;

typedef unsigned short ushort_t;
typedef unsigned int uint_t;
typedef __attribute__((ext_vector_type(8))) short bf16x8;
typedef __attribute__((ext_vector_type(4))) float f32x4;

__device__ __forceinline__ float bf2f(ushort_t u) {
    union { float f; uint_t ui; } c; c.ui = ((uint_t)u) << 16; return c.f;
}
__device__ __forceinline__ ushort_t f2bf(float f) {
    uint_t u = __float_as_uint(f);
    return (ushort_t)((u + 0x7FFFu + ((u >> 16) & 1u)) >> 16);  // RNE
}

// ---------------- CSR build (by dst), once per call ----------------
__global__ void k_count_deg(const int* __restrict__ dst, int* __restrict__ deg) {
    int e4 = blockIdx.x * 256 + threadIdx.x;
    if (e4 * 4 >= N_EDGES) return;
    int4 d = ((const int4*)dst)[e4];
    atomicAdd(&deg[d.x], 1); atomicAdd(&deg[d.y], 1);
    atomicAdd(&deg[d.z], 1); atomicAdd(&deg[d.w], 1);
}

__global__ void k_scan_block(const int* __restrict__ deg, int* __restrict__ rowptr,
                             int* __restrict__ bsum) {
    __shared__ int s[256];
    int i = blockIdx.x * 256 + threadIdx.x;
    int v = (i < N_NODES) ? deg[i] : 0;
    s[threadIdx.x] = v;
    __syncthreads();
    for (int off = 1; off < 256; off <<= 1) {
        int t = (threadIdx.x >= off) ? s[threadIdx.x - off] : 0;
        __syncthreads();
        s[threadIdx.x] += t;
        __syncthreads();
    }
    if (i < N_NODES) rowptr[i] = s[threadIdx.x] - v;
    if (threadIdx.x == 255) bsum[blockIdx.x] = s[255];
}

__global__ void k_scan_bsum(int* __restrict__ bsum, int nb) {
    __shared__ int s[256];
    int t = threadIdx.x;
    int v = (t < nb) ? bsum[t] : 0;
    s[t] = v;
    __syncthreads();
    for (int off = 1; off < 256; off <<= 1) {
        int tv = (t >= off) ? s[t - off] : 0;
        __syncthreads();
        s[t] += tv;
        __syncthreads();
    }
    if (t < nb) bsum[t] = s[t] - v;
}

__global__ void k_scan_add(int* __restrict__ rowptr, const int* __restrict__ bsum) {
    int i = blockIdx.x * 256 + threadIdx.x;
    if (i < N_NODES) rowptr[i] += bsum[blockIdx.x];
    if (i == 0) rowptr[N_NODES] = N_EDGES;
}

__global__ void k_scatter(const int* __restrict__ src, const int* __restrict__ dst,
                          const int* __restrict__ rowptr, int* __restrict__ fill,
                          int* __restrict__ srcs, int* __restrict__ eidxp,
                          int* __restrict__ pdst) {
    int e4 = blockIdx.x * 256 + threadIdx.x;
    if (e4 * 4 >= N_EDGES) return;
    int4 s = ((const int4*)src)[e4];
    int4 d = ((const int4*)dst)[e4];
    int e0 = e4 * 4;
    int p0 = rowptr[d.x] + atomicAdd(&fill[d.x], 1);
    srcs[p0] = s.x; eidxp[p0] = e0;     pdst[p0] = d.x;
    int p1 = rowptr[d.y] + atomicAdd(&fill[d.y], 1);
    srcs[p1] = s.y; eidxp[p1] = e0 + 1; pdst[p1] = d.y;
    int p2 = rowptr[d.z] + atomicAdd(&fill[d.z], 1);
    srcs[p2] = s.z; eidxp[p2] = e0 + 2; pdst[p2] = d.z;
    int p3 = rowptr[d.w] + atomicAdd(&fill[d.w], 1);
    srcs[p3] = s.w; eidxp[p3] = e0 + 3; pdst[p3] = d.w;
}

// ---- permute eattr into CSR order, fp32 -> bf16 (layer-invariant, once) ----
__global__ void k_perm(const int* __restrict__ eidxp, const float* __restrict__ eattr,
                       ushort_t* __restrict__ ea) {
    int tid = blockIdx.x * 256 + threadIdx.x;
    int p = tid >> 2, q = tid & 3;
    if (p >= N_EDGES) return;
    int e = eidxp[p];
    float4 v = *(const float4*)(eattr + (size_t)e * ED + q * 4);
    uint_t lo = (uint_t)f2bf(v.x) | ((uint_t)f2bf(v.y) << 16);
    uint_t hi = (uint_t)f2bf(v.z) | ((uint_t)f2bf(v.w) << 16);
    *(uint2*)(ea + (size_t)p * ED + q * 4) = make_uint2(lo, hi);
}

// ---------------- proj: h = x @ proj_w + proj_b  (K=32) ----------------
__global__ __launch_bounds__(192) void k_proj(const float* __restrict__ x,
                                              const float* __restrict__ pw,
                                              const float* __restrict__ pb,
                                              float* __restrict__ h) {
    int t = threadIdx.x;
    int c = t % 96, half = t / 96;
    float wreg[ND];
#pragma unroll
    for (int k = 0; k < ND; k++) wreg[k] = pw[k * HID + c];
    float b = pb[c];
    int n0 = blockIdx.x * 16 + half * 8;
    for (int i = 0; i < 8; i += 2) {
        int na = n0 + i, nb = na + 1;
        const float4* xa = (const float4*)(x + (size_t)na * ND);
        const float4* xb = (const float4*)(x + (size_t)nb * ND);
        float accA = b, accB = b;
#pragma unroll
        for (int k4 = 0; k4 < ND / 4; k4++) {
            float4 va = xa[k4], vb = xb[k4];
            accA += va.x * wreg[4 * k4] + va.y * wreg[4 * k4 + 1] +
                    va.z * wreg[4 * k4 + 2] + va.w * wreg[4 * k4 + 3];
            accB += vb.x * wreg[4 * k4] + vb.y * wreg[4 * k4 + 1] +
                    vb.z * wreg[4 * k4 + 2] + vb.w * wreg[4 * k4 + 3];
        }
        h[(size_t)na * HID + c] = accA;
        h[(size_t)nb * HID + c] = accB;
    }
}

// ---- k_linlr_mfma: [xl|xr] = h @ [Wl|Wr] + [bl|br], bf16 out, MFMA ----
// Block = 256 thr = 4 waves, 64 nodes. W' (96x192) staged bf16-transposed in
// LDS as WT[n][k], stride 104 (pad 8 -> 52-dword row stride, 2-way = free).
// Wave: 16 nodes; A-frags from fp32 h on the fly (A[m=lane&15][k=quad*8+j]);
// 12 n-tiles x 3 K-steps of mfma_f32_16x16x32_bf16.
// D layout: col(lane&15)=channel-in-tile, row(quad*4+reg)=node-in-tile.
__global__ __launch_bounds__(256) void k_linlr_mfma(
    const float* __restrict__ h, const float* __restrict__ Wl,
    const float* __restrict__ bl, const float* __restrict__ Wr,
    const float* __restrict__ br, ushort_t* __restrict__ xl,
    ushort_t* __restrict__ xr) {
    __shared__ ushort_t sW[192 * 104];
    __shared__ float sB[192];
    int t = threadIdx.x;

    // stage W' -> LDS transposed bf16 (18432 = 72 * 256 exactly)
    for (int idx = t; idx < 192 * 96; idx += 256) {
        int n = idx % 192, k = idx / 192;
        float v = (n < 96) ? Wl[k * 96 + n] : Wr[k * 96 + (n - 96)];
        sW[n * 104 + k] = f2bf(v);
    }
    if (t < 192) sB[t] = (t < 96) ? bl[t] : br[t - 96];
    __syncthreads();

    int wv = t >> 6, lane = t & 63;
    int m0 = blockIdx.x * 64 + wv * 16;
    if (m0 >= N_NODES) return;   // after syncthreads; no further barriers
    int m = lane & 15, quad = lane >> 4;

    // A-frags: 3 K-steps, convert fp32 h -> bf16
    bf16x8 afr[3];
    const float* hrow = h + (size_t)(m0 + m) * HID;
#pragma unroll
    for (int s = 0; s < 3; s++) {
        float4 v0 = *(const float4*)(hrow + s * 32 + quad * 8);
        float4 v1 = *(const float4*)(hrow + s * 32 + quad * 8 + 4);
        bf16x8 a;
        a[0] = (short)f2bf(v0.x); a[1] = (short)f2bf(v0.y);
        a[2] = (short)f2bf(v0.z); a[3] = (short)f2bf(v0.w);
        a[4] = (short)f2bf(v1.x); a[5] = (short)f2bf(v1.y);
        a[6] = (short)f2bf(v1.z); a[7] = (short)f2bf(v1.w);
        afr[s] = a;
    }

#pragma unroll
    for (int nt = 0; nt < 12; nt++) {
        int ch = nt * 16 + m;   // channel this lane's column maps to
        f32x4 acc = {0.f, 0.f, 0.f, 0.f};
#pragma unroll
        for (int s = 0; s < 3; s++) {
            bf16x8 bfr = *(const bf16x8*)(sW + (nt * 16 + m) * 104 + s * 32 + quad * 8);
            acc = __builtin_amdgcn_mfma_f32_16x16x32_bf16(afr[s], bfr, acc, 0, 0, 0);
        }
        float bias = sB[ch];
        ushort_t* dst = (ch < 96) ? (xl + (size_t)(m0 + quad * 4) * HID + ch)
                                  : (xr + (size_t)(m0 + quad * 4) * HID + (ch - 96));
#pragma unroll
        for (int r = 0; r < 4; r++)
            dst[(size_t)r * HID] = f2bf(acc[r] + bias);
    }
}

// ---- k_ev: edge-parallel attention weights via MFMA ----
__global__ __launch_bounds__(256) void k_ev(
    const ushort_t* __restrict__ xlb, const ushort_t* __restrict__ xrb,
    const ushort_t* __restrict__ ea, const int* __restrict__ srcs,
    const int* __restrict__ pdst, const float* __restrict__ WeL,
    const float* __restrict__ attL, float4* __restrict__ ev) {
    int wid = blockIdx.x * 4 + (threadIdx.x >> 6);
    int lane = threadIdx.x & 63;
    int col = lane & 15, quad = lane >> 4;

    bf16x8 afr[6];
#pragma unroll
    for (int mc = 0; mc < 6; mc++) {
        bf16x8 a = {0, 0, 0, 0, 0, 0, 0, 0};
        if (quad < 2) {
#pragma unroll
            for (int j = 0; j < 8; j++)
                a[j] = (short)f2bf(WeL[(quad * 8 + j) * HID + mc * 16 + col]);
        }
        afr[mc] = a;
    }
    float attr[6][4];
#pragma unroll
    for (int mc = 0; mc < 6; mc++)
#pragma unroll
        for (int r = 0; r < 4; r++)
            attr[mc][r] = attL[mc * 16 + quad * 4 + r];

#pragma unroll 2
    for (int b = 0; b < 8; b++) {
        int p0 = wid * 128 + b * 16;
        if (p0 >= N_EDGES) continue;
        int p = p0 + col;
        bf16x8 bfr = {0, 0, 0, 0, 0, 0, 0, 0};
        if (quad < 2)
            bfr = *(const bf16x8*)(ea + (size_t)p * ED + quad * 8);
        f32x4 zero4 = {0.f, 0.f, 0.f, 0.f};
        f32x4 d[6];
#pragma unroll
        for (int mc = 0; mc < 6; mc++)
            d[mc] = __builtin_amdgcn_mfma_f32_16x16x32_bf16(afr[mc], bfr, zero4, 0, 0, 0);

        int src = srcs[p], dst = pdst[p];
        float s[6];
#pragma unroll
        for (int mc = 0; mc < 6; mc++) {
            int cb = mc * 16 + quad * 4;
            uint2 xu = *(const uint2*)(xlb + (size_t)src * HID + cb);
            uint2 ru = *(const uint2*)(xrb + (size_t)dst * HID + cb);
            float x0 = bf2f((ushort_t)(xu.x & 0xffff)), x1 = bf2f((ushort_t)(xu.x >> 16));
            float x2 = bf2f((ushort_t)(xu.y & 0xffff)), x3 = bf2f((ushort_t)(xu.y >> 16));
            float r0 = bf2f((ushort_t)(ru.x & 0xffff)), r1 = bf2f((ushort_t)(ru.x >> 16));
            float r2 = bf2f((ushort_t)(ru.y & 0xffff)), r3 = bf2f((ushort_t)(ru.y >> 16));
            float z0 = x0 + r0 + d[mc][0]; z0 = z0 > 0.f ? z0 : 0.2f * z0;
            float z1 = x1 + r1 + d[mc][1]; z1 = z1 > 0.f ? z1 : 0.2f * z1;
            float z2 = x2 + r2 + d[mc][2]; z2 = z2 > 0.f ? z2 : 0.2f * z2;
            float z3 = x3 + r3 + d[mc][3]; z3 = z3 > 0.f ? z3 : 0.2f * z3;
            s[mc] = z0 * attr[mc][0] + z1 * attr[mc][1] +
                    z2 * attr[mc][2] + z3 * attr[mc][3];
        }
        float U[6], V[6];
#pragma unroll
        for (int mc = 0; mc < 6; mc++) {
            U[mc] = s[mc] + __shfl_xor(s[mc], 16);
            V[mc] = U[mc] + __shfl_xor(U[mc], 32);
        }
        if (quad == 0) {
            float h0 = V[0] + U[1];
            float h1 = (V[1] - U[1]) + V[2];
            float h2 = V[3] + U[4];
            float h3 = (V[4] - U[4]) + V[5];
            ev[p] = make_float4(__expf(h0), __expf(h1), __expf(h2), __expf(h3));
        }
    }
}

// ---- k_agg: weighted sum + residual + LayerNorm ----
__global__ __launch_bounds__(256) void k_agg(
    const ushort_t* __restrict__ xlb, const float* __restrict__ evf,
    const int* __restrict__ srcs, const int* __restrict__ rowptr,
    const float* __restrict__ convb, const float* __restrict__ lng,
    const float* __restrict__ lnb, float* __restrict__ h) {
    int lane = threadIdx.x & 63;
    int node = blockIdx.x * 4 + (threadIdx.x >> 6);
    int slot = lane >> 4, q = lane & 15;
    int c0 = q * 6, head = q >> 2;
    int beg = rowptr[node], end = rowptr[node + 1];
    int cnt = (end - beg + 3) >> 2;

    float n0 = 0.f, n1 = 0.f, n2 = 0.f, n3 = 0.f, n4 = 0.f, n5 = 0.f, den = 0.f;
    if (cnt > 0) {
        int p = beg + slot;
        bool v = p < end;
        int pc = v ? p : beg;
        int src = srcs[pc];
        float evv = evf[4 * pc + head];
        const ushort_t* xp = xlb + (size_t)src * HID + c0;
        uint_t a0 = *(const uint_t*)(xp);
        uint_t a1 = *(const uint_t*)(xp + 2);
        uint_t a2 = *(const uint_t*)(xp + 4);
        for (int it = 0; it < cnt; ++it) {
            int pn = beg + (it + 1) * 4 + slot;
            bool vn = pn < end;
            int pcn = vn ? pn : beg;
            int srcn = srcs[pcn];
            float evn = evf[4 * pcn + head];
            const ushort_t* xpn = xlb + (size_t)srcn * HID + c0;
            uint_t b0 = *(const uint_t*)(xpn);
            uint_t b1 = *(const uint_t*)(xpn + 2);
            uint_t b2 = *(const uint_t*)(xpn + 4);

            float e = v ? evv : 0.f;
            n0 += e * bf2f((ushort_t)(a0 & 0xffff));
            n1 += e * bf2f((ushort_t)(a0 >> 16));
            n2 += e * bf2f((ushort_t)(a1 & 0xffff));
            n3 += e * bf2f((ushort_t)(a1 >> 16));
            n4 += e * bf2f((ushort_t)(a2 & 0xffff));
            n5 += e * bf2f((ushort_t)(a2 >> 16));
            den += e;

            v = vn; evv = evn; a0 = b0; a1 = b1; a2 = b2;
        }
    }
    n0 += __shfl_xor(n0, 16); n0 += __shfl_xor(n0, 32);
    n1 += __shfl_xor(n1, 16); n1 += __shfl_xor(n1, 32);
    n2 += __shfl_xor(n2, 16); n2 += __shfl_xor(n2, 32);
    n3 += __shfl_xor(n3, 16); n3 += __shfl_xor(n3, 32);
    n4 += __shfl_xor(n4, 16); n4 += __shfl_xor(n4, 32);
    n5 += __shfl_xor(n5, 16); n5 += __shfl_xor(n5, 32);
    den += __shfl_xor(den, 16); den += __shfl_xor(den, 32);

    size_t nb = (size_t)node * HID + c0;
    float inv = 1.f / (den + 1e-16f);
    float v0 = h[nb + 0] + n0 * inv + convb[c0 + 0];
    float v1 = h[nb + 1] + n1 * inv + convb[c0 + 1];
    float v2 = h[nb + 2] + n2 * inv + convb[c0 + 2];
    float v3 = h[nb + 3] + n3 * inv + convb[c0 + 3];
    float v4 = h[nb + 4] + n4 * inv + convb[c0 + 4];
    float v5 = h[nb + 5] + n5 * inv + convb[c0 + 5];
    float sm = v0 + v1 + v2 + v3 + v4 + v5;
    sm += __shfl_xor(sm, 1); sm += __shfl_xor(sm, 2);
    sm += __shfl_xor(sm, 4); sm += __shfl_xor(sm, 8);
    float mu = sm * (1.f / 96.f);
    float d0 = v0 - mu, d1 = v1 - mu, d2 = v2 - mu;
    float d3 = v3 - mu, d4 = v4 - mu, d5 = v5 - mu;
    float sv = d0 * d0 + d1 * d1 + d2 * d2 + d3 * d3 + d4 * d4 + d5 * d5;
    sv += __shfl_xor(sv, 1); sv += __shfl_xor(sv, 2);
    sv += __shfl_xor(sv, 4); sv += __shfl_xor(sv, 8);
    float rstd = rsqrtf(sv * (1.f / 96.f) + 1e-5f);
    if (slot == 0) {
        h[nb + 0] = d0 * rstd * lng[c0 + 0] + lnb[c0 + 0];
        h[nb + 1] = d1 * rstd * lng[c0 + 1] + lnb[c0 + 1];
        h[nb + 2] = d2 * rstd * lng[c0 + 2] + lnb[c0 + 2];
        h[nb + 3] = d3 * rstd * lng[c0 + 3] + lnb[c0 + 3];
        h[nb + 4] = d4 * rstd * lng[c0 + 4] + lnb[c0 + 4];
        h[nb + 5] = d5 * rstd * lng[c0 + 5] + lnb[c0 + 5];
    }
}

// ---------------- head: gelu(h@W1+b1)@W2+b2, 4 threads per node ----------------
__global__ __launch_bounds__(256) void k_head(const float* __restrict__ h,
                                              const float* __restrict__ W1,
                                              const float* __restrict__ b1,
                                              const float* __restrict__ W2,
                                              const float* __restrict__ b2,
                                              float* __restrict__ out) {
    int gid = blockIdx.x * 256 + threadIdx.x;
    int n = gid >> 2, q = gid & 3;
    if (n >= N_NODES) return;
    float hr[HID];
    const float4* h4 = (const float4*)(h + (size_t)n * HID);
#pragma unroll
    for (int i = 0; i < HID / 4; i++) {
        float4 v = h4[i];
        hr[4 * i] = v.x; hr[4 * i + 1] = v.y; hr[4 * i + 2] = v.z; hr[4 * i + 3] = v.w;
    }
    const float inv_sqrt2 = 0.70710678118654752f;
    float y = 0.f;
    int j0 = q * 12;
    for (int g = 0; g < 3; g++) {
        int j = j0 + 4 * g;
        float4 acc = make_float4(b1[j], b1[j + 1], b1[j + 2], b1[j + 3]);
#pragma unroll
        for (int k = 0; k < HID; k++) {
            float4 w = *(const float4*)(W1 + k * 48 + j);
            acc.x += hr[k] * w.x; acc.y += hr[k] * w.y;
            acc.z += hr[k] * w.z; acc.w += hr[k] * w.w;
        }
        float g0 = 0.5f * acc.x * (1.f + erff(acc.x * inv_sqrt2));
        float g1 = 0.5f * acc.y * (1.f + erff(acc.y * inv_sqrt2));
        float g2 = 0.5f * acc.z * (1.f + erff(acc.z * inv_sqrt2));
        float g3 = 0.5f * acc.w * (1.f + erff(acc.w * inv_sqrt2));
        y += g0 * W2[j] + g1 * W2[j + 1] + g2 * W2[j + 2] + g3 * W2[j + 3];
    }
    y += __shfl_xor(y, 1);
    y += __shfl_xor(y, 2);
    if (q == 0) out[n] = y + b2[0];
}

extern "C" void kernel_launch(void* const* d_in, const int* in_sizes, int n_in,
                              void* d_out, int out_size, void* d_ws, size_t ws_size,
                              hipStream_t stream) {
    const float* x       = (const float*)d_in[0];
    const int*   eidx    = (const int*)  d_in[1];
    const float* eattr   = (const float*)d_in[2];
    const float* proj_w  = (const float*)d_in[3];
    const float* proj_b  = (const float*)d_in[4];
    const float* lin_l_w = (const float*)d_in[5];
    const float* lin_l_b = (const float*)d_in[6];
    const float* lin_r_w = (const float*)d_in[7];
    const float* lin_r_b = (const float*)d_in[8];
    const float* lin_e_w = (const float*)d_in[9];
    const float* att     = (const float*)d_in[10];
    const float* conv_b  = (const float*)d_in[11];
    const float* ln_g    = (const float*)d_in[12];
    const float* ln_b    = (const float*)d_in[13];
    const float* head_w1 = (const float*)d_in[14];
    const float* head_b1 = (const float*)d_in[15];
    const float* head_w2 = (const float*)d_in[16];
    const float* head_b2 = (const float*)d_in[17];
    float* out = (float*)d_out;

    char* p = (char*)d_ws;
    auto alloc = [&](size_t bytes) -> char* {
        char* r = p;
        p += (bytes + 255) & ~size_t(255);
        return r;
    };
    float*    h      = (float*)alloc(sizeof(float) * (size_t)N_NODES * HID);
    ushort_t* xl     = (ushort_t*)alloc(2 * (size_t)N_NODES * HID);
    ushort_t* xr     = (ushort_t*)alloc(2 * (size_t)N_NODES * HID);
    int*      deg    = (int*)alloc(4 * (size_t)N_NODES);
    int*      fill   = (int*)alloc(4 * (size_t)N_NODES);
    int*      rowptr = (int*)alloc(4 * (size_t)(N_NODES + 1));
    int*      bsum   = (int*)alloc(4 * 256);
    int*      srcs   = (int*)alloc(4 * (size_t)N_EDGES);
    int*      eidxp  = (int*)alloc(4 * (size_t)N_EDGES);
    int*      pdst   = (int*)alloc(4 * (size_t)N_EDGES);
    ushort_t* ea_csr = (ushort_t*)alloc(2 * (size_t)N_EDGES * ED);
    float4*   ev     = (float4*)alloc(16 * (size_t)N_EDGES);

    const int* srcA = eidx;
    const int* dstA = eidx + N_EDGES;

    int ebl4 = (N_EDGES / 4 + 255) / 256;  // 782
    int nbl  = (N_NODES + 255) / 256;      // 196

    hipMemsetAsync(deg, 0, 4 * (size_t)N_NODES, stream);
    hipMemsetAsync(fill, 0, 4 * (size_t)N_NODES, stream);
    k_count_deg<<<ebl4, 256, 0, stream>>>(dstA, deg);
    k_scan_block<<<nbl, 256, 0, stream>>>(deg, rowptr, bsum);
    k_scan_bsum<<<1, 256, 0, stream>>>(bsum, nbl);
    k_scan_add<<<nbl, 256, 0, stream>>>(rowptr, bsum);
    k_scatter<<<ebl4, 256, 0, stream>>>(srcA, dstA, rowptr, fill, srcs, eidxp, pdst);
    k_perm<<<(N_EDGES * 4) / 256, 256, 0, stream>>>(eidxp, eattr, ea_csr);

    k_proj<<<N_NODES / 16, 192, 0, stream>>>(x, proj_w, proj_b, h);
    for (int l = 0; l < NLAYER; l++) {
        k_linlr_mfma<<<(N_NODES + 63) / 64, 256, 0, stream>>>(
            h, lin_l_w + (size_t)l * HID * HID, lin_l_b + (size_t)l * HID,
            lin_r_w + (size_t)l * HID * HID, lin_r_b + (size_t)l * HID, xl, xr);
        k_ev<<<1563, 256, 0, stream>>>(xl, xr, ea_csr, srcs, pdst,
                                       lin_e_w + (size_t)l * ED * HID,
                                       att + (size_t)l * HID,
                                       (float4*)ev);
        k_agg<<<N_NODES / 4, 256, 0, stream>>>(
            xl, (const float*)ev, srcs, rowptr, conv_b + (size_t)l * HID,
            ln_g + (size_t)l * HID, ln_b + (size_t)l * HID, h);
    }
    k_head<<<(N_NODES * 4 + 255) / 256, 256, 0, stream>>>(h, head_w1, head_b1,
                                                          head_w2, head_b2, out);
}

// Round 5
// 608.440 us; speedup vs baseline: 2.5753x; 1.1093x over previous
//
#include <hip/hip_runtime.h>

constexpr int N_NODES = 50000;
constexpr int N_EDGES = 800000;
constexpr int ND  = 32;
constexpr int ED  = 16;
constexpr int HID = 96;
constexpr int NLAYER = 3;

typedef unsigned short ushort_t;
typedef unsigned int uint_t;
typedef __attribute__((ext_vector_type(8))) short bf16x8;
typedef __attribute__((ext_vector_type(4))) float f32x4;

__device__ __forceinline__ float bf2f(ushort_t u) {
    union { float f; uint_t ui; } c; c.ui = ((uint_t)u) << 16; return c.f;
}
__device__ __forceinline__ ushort_t f2bf(float f) {
    uint_t u = __float_as_uint(f);
    return (ushort_t)((u + 0x7FFFu + ((u >> 16) & 1u)) >> 16);  // RNE
}

// ---------------- CSR build (by dst), once per call ----------------
__global__ void k_count_deg(const int* __restrict__ dst, int* __restrict__ deg) {
    int e4 = blockIdx.x * 256 + threadIdx.x;
    if (e4 * 4 >= N_EDGES) return;
    int4 d = ((const int4*)dst)[e4];
    atomicAdd(&deg[d.x], 1); atomicAdd(&deg[d.y], 1);
    atomicAdd(&deg[d.z], 1); atomicAdd(&deg[d.w], 1);
}

__global__ void k_scan_block(const int* __restrict__ deg, int* __restrict__ rowptr,
                             int* __restrict__ bsum) {
    __shared__ int s[256];
    int i = blockIdx.x * 256 + threadIdx.x;
    int v = (i < N_NODES) ? deg[i] : 0;
    s[threadIdx.x] = v;
    __syncthreads();
    for (int off = 1; off < 256; off <<= 1) {
        int t = (threadIdx.x >= off) ? s[threadIdx.x - off] : 0;
        __syncthreads();
        s[threadIdx.x] += t;
        __syncthreads();
    }
    if (i < N_NODES) rowptr[i] = s[threadIdx.x] - v;
    if (threadIdx.x == 255) bsum[blockIdx.x] = s[255];
}

__global__ void k_scan_bsum(int* __restrict__ bsum, int nb) {
    __shared__ int s[256];
    int t = threadIdx.x;
    int v = (t < nb) ? bsum[t] : 0;
    s[t] = v;
    __syncthreads();
    for (int off = 1; off < 256; off <<= 1) {
        int tv = (t >= off) ? s[t - off] : 0;
        __syncthreads();
        s[t] += tv;
        __syncthreads();
    }
    if (t < nb) bsum[t] = s[t] - v;
}

__global__ void k_scan_add(int* __restrict__ rowptr, const int* __restrict__ bsum) {
    int i = blockIdx.x * 256 + threadIdx.x;
    if (i < N_NODES) rowptr[i] += bsum[blockIdx.x];
    if (i == 0) rowptr[N_NODES] = N_EDGES;
}

__global__ void k_scatter(const int* __restrict__ src, const int* __restrict__ dst,
                          const int* __restrict__ rowptr, int* __restrict__ fill,
                          int* __restrict__ srcs, int* __restrict__ eidxp,
                          int* __restrict__ pdst) {
    int e4 = blockIdx.x * 256 + threadIdx.x;
    if (e4 * 4 >= N_EDGES) return;
    int4 s = ((const int4*)src)[e4];
    int4 d = ((const int4*)dst)[e4];
    int e0 = e4 * 4;
    int p0 = rowptr[d.x] + atomicAdd(&fill[d.x], 1);
    srcs[p0] = s.x; eidxp[p0] = e0;     pdst[p0] = d.x;
    int p1 = rowptr[d.y] + atomicAdd(&fill[d.y], 1);
    srcs[p1] = s.y; eidxp[p1] = e0 + 1; pdst[p1] = d.y;
    int p2 = rowptr[d.z] + atomicAdd(&fill[d.z], 1);
    srcs[p2] = s.z; eidxp[p2] = e0 + 2; pdst[p2] = d.z;
    int p3 = rowptr[d.w] + atomicAdd(&fill[d.w], 1);
    srcs[p3] = s.w; eidxp[p3] = e0 + 3; pdst[p3] = d.w;
}

// ---- permute eattr into CSR order, fp32 -> bf16 (layer-invariant, once) ----
__global__ void k_perm(const int* __restrict__ eidxp, const float* __restrict__ eattr,
                       ushort_t* __restrict__ ea) {
    int tid = blockIdx.x * 256 + threadIdx.x;
    int p = tid >> 2, q = tid & 3;
    if (p >= N_EDGES) return;
    int e = eidxp[p];
    float4 v = *(const float4*)(eattr + (size_t)e * ED + q * 4);
    uint_t lo = (uint_t)f2bf(v.x) | ((uint_t)f2bf(v.y) << 16);
    uint_t hi = (uint_t)f2bf(v.z) | ((uint_t)f2bf(v.w) << 16);
    *(uint2*)(ea + (size_t)p * ED + q * 4) = make_uint2(lo, hi);
}

// ---------------- proj: h = x @ proj_w + proj_b  (K=32) ----------------
__global__ __launch_bounds__(192) void k_proj(const float* __restrict__ x,
                                              const float* __restrict__ pw,
                                              const float* __restrict__ pb,
                                              float* __restrict__ h) {
    int t = threadIdx.x;
    int c = t % 96, half = t / 96;
    float wreg[ND];
#pragma unroll
    for (int k = 0; k < ND; k++) wreg[k] = pw[k * HID + c];
    float b = pb[c];
    int n0 = blockIdx.x * 16 + half * 8;
    for (int i = 0; i < 8; i += 2) {
        int na = n0 + i, nb = na + 1;
        const float4* xa = (const float4*)(x + (size_t)na * ND);
        const float4* xb = (const float4*)(x + (size_t)nb * ND);
        float accA = b, accB = b;
#pragma unroll
        for (int k4 = 0; k4 < ND / 4; k4++) {
            float4 va = xa[k4], vb = xb[k4];
            accA += va.x * wreg[4 * k4] + va.y * wreg[4 * k4 + 1] +
                    va.z * wreg[4 * k4 + 2] + va.w * wreg[4 * k4 + 3];
            accB += vb.x * wreg[4 * k4] + vb.y * wreg[4 * k4 + 1] +
                    vb.z * wreg[4 * k4 + 2] + vb.w * wreg[4 * k4 + 3];
        }
        h[(size_t)na * HID + c] = accA;
        h[(size_t)nb * HID + c] = accB;
    }
}

// ---- k_linlr_mfma: [xl|xr] = h @ [Wl|Wr] + [bl|br], bf16 out, MFMA ----
__global__ __launch_bounds__(256) void k_linlr_mfma(
    const float* __restrict__ h, const float* __restrict__ Wl,
    const float* __restrict__ bl, const float* __restrict__ Wr,
    const float* __restrict__ br, ushort_t* __restrict__ xl,
    ushort_t* __restrict__ xr) {
    __shared__ ushort_t sW[192 * 104];
    __shared__ float sB[192];
    int t = threadIdx.x;

    for (int idx = t; idx < 192 * 96; idx += 256) {
        int n = idx % 192, k = idx / 192;
        float v = (n < 96) ? Wl[k * 96 + n] : Wr[k * 96 + (n - 96)];
        sW[n * 104 + k] = f2bf(v);
    }
    if (t < 192) sB[t] = (t < 96) ? bl[t] : br[t - 96];
    __syncthreads();

    int wv = t >> 6, lane = t & 63;
    int m0 = blockIdx.x * 64 + wv * 16;
    if (m0 >= N_NODES) return;
    int m = lane & 15, quad = lane >> 4;

    bf16x8 afr[3];
    const float* hrow = h + (size_t)(m0 + m) * HID;
#pragma unroll
    for (int s = 0; s < 3; s++) {
        float4 v0 = *(const float4*)(hrow + s * 32 + quad * 8);
        float4 v1 = *(const float4*)(hrow + s * 32 + quad * 8 + 4);
        bf16x8 a;
        a[0] = (short)f2bf(v0.x); a[1] = (short)f2bf(v0.y);
        a[2] = (short)f2bf(v0.z); a[3] = (short)f2bf(v0.w);
        a[4] = (short)f2bf(v1.x); a[5] = (short)f2bf(v1.y);
        a[6] = (short)f2bf(v1.z); a[7] = (short)f2bf(v1.w);
        afr[s] = a;
    }

#pragma unroll
    for (int nt = 0; nt < 12; nt++) {
        int ch = nt * 16 + m;
        f32x4 acc = {0.f, 0.f, 0.f, 0.f};
#pragma unroll
        for (int s = 0; s < 3; s++) {
            bf16x8 bfr = *(const bf16x8*)(sW + (nt * 16 + m) * 104 + s * 32 + quad * 8);
            acc = __builtin_amdgcn_mfma_f32_16x16x32_bf16(afr[s], bfr, acc, 0, 0, 0);
        }
        float bias = sB[ch];
        ushort_t* dst = (ch < 96) ? (xl + (size_t)(m0 + quad * 4) * HID + ch)
                                  : (xr + (size_t)(m0 + quad * 4) * HID + (ch - 96));
#pragma unroll
        for (int r = 0; r < 4; r++)
            dst[(size_t)r * HID] = f2bf(acc[r] + bias);
    }
}

// ---- k_ev: edge-parallel attention weights via MFMA ----
__global__ __launch_bounds__(256) void k_ev(
    const ushort_t* __restrict__ xlb, const ushort_t* __restrict__ xrb,
    const ushort_t* __restrict__ ea, const int* __restrict__ srcs,
    const int* __restrict__ pdst, const float* __restrict__ WeL,
    const float* __restrict__ attL, float4* __restrict__ ev) {
    int wid = blockIdx.x * 4 + (threadIdx.x >> 6);
    int lane = threadIdx.x & 63;
    int col = lane & 15, quad = lane >> 4;

    bf16x8 afr[6];
#pragma unroll
    for (int mc = 0; mc < 6; mc++) {
        bf16x8 a = {0, 0, 0, 0, 0, 0, 0, 0};
        if (quad < 2) {
#pragma unroll
            for (int j = 0; j < 8; j++)
                a[j] = (short)f2bf(WeL[(quad * 8 + j) * HID + mc * 16 + col]);
        }
        afr[mc] = a;
    }
    float attr[6][4];
#pragma unroll
    for (int mc = 0; mc < 6; mc++)
#pragma unroll
        for (int r = 0; r < 4; r++)
            attr[mc][r] = attL[mc * 16 + quad * 4 + r];

#pragma unroll 2
    for (int b = 0; b < 8; b++) {
        int p0 = wid * 128 + b * 16;
        if (p0 >= N_EDGES) continue;
        int p = p0 + col;
        bf16x8 bfr = {0, 0, 0, 0, 0, 0, 0, 0};
        if (quad < 2)
            bfr = *(const bf16x8*)(ea + (size_t)p * ED + quad * 8);
        f32x4 zero4 = {0.f, 0.f, 0.f, 0.f};
        f32x4 d[6];
#pragma unroll
        for (int mc = 0; mc < 6; mc++)
            d[mc] = __builtin_amdgcn_mfma_f32_16x16x32_bf16(afr[mc], bfr, zero4, 0, 0, 0);

        int src = srcs[p], dst = pdst[p];
        float s[6];
#pragma unroll
        for (int mc = 0; mc < 6; mc++) {
            int cb = mc * 16 + quad * 4;
            uint2 xu = *(const uint2*)(xlb + (size_t)src * HID + cb);
            uint2 ru = *(const uint2*)(xrb + (size_t)dst * HID + cb);
            float x0 = bf2f((ushort_t)(xu.x & 0xffff)), x1 = bf2f((ushort_t)(xu.x >> 16));
            float x2 = bf2f((ushort_t)(xu.y & 0xffff)), x3 = bf2f((ushort_t)(xu.y >> 16));
            float r0 = bf2f((ushort_t)(ru.x & 0xffff)), r1 = bf2f((ushort_t)(ru.x >> 16));
            float r2 = bf2f((ushort_t)(ru.y & 0xffff)), r3 = bf2f((ushort_t)(ru.y >> 16));
            float z0 = x0 + r0 + d[mc][0]; z0 = z0 > 0.f ? z0 : 0.2f * z0;
            float z1 = x1 + r1 + d[mc][1]; z1 = z1 > 0.f ? z1 : 0.2f * z1;
            float z2 = x2 + r2 + d[mc][2]; z2 = z2 > 0.f ? z2 : 0.2f * z2;
            float z3 = x3 + r3 + d[mc][3]; z3 = z3 > 0.f ? z3 : 0.2f * z3;
            s[mc] = z0 * attr[mc][0] + z1 * attr[mc][1] +
                    z2 * attr[mc][2] + z3 * attr[mc][3];
        }
        float U[6], V[6];
#pragma unroll
        for (int mc = 0; mc < 6; mc++) {
            U[mc] = s[mc] + __shfl_xor(s[mc], 16);
            V[mc] = U[mc] + __shfl_xor(U[mc], 32);
        }
        if (quad == 0) {
            float h0 = V[0] + U[1];
            float h1 = (V[1] - U[1]) + V[2];
            float h2 = V[3] + U[4];
            float h3 = (V[4] - U[4]) + V[5];
            ev[p] = make_float4(__expf(h0), __expf(h1), __expf(h2), __expf(h3));
        }
    }
}

// ---- k_agg: weighted sum + residual + LayerNorm ----
__global__ __launch_bounds__(256) void k_agg(
    const ushort_t* __restrict__ xlb, const float* __restrict__ evf,
    const int* __restrict__ srcs, const int* __restrict__ rowptr,
    const float* __restrict__ convb, const float* __restrict__ lng,
    const float* __restrict__ lnb, float* __restrict__ h) {
    int lane = threadIdx.x & 63;
    int node = blockIdx.x * 4 + (threadIdx.x >> 6);
    int slot = lane >> 4, q = lane & 15;
    int c0 = q * 6, head = q >> 2;
    int beg = rowptr[node], end = rowptr[node + 1];
    int cnt = (end - beg + 3) >> 2;

    float n0 = 0.f, n1 = 0.f, n2 = 0.f, n3 = 0.f, n4 = 0.f, n5 = 0.f, den = 0.f;
    if (cnt > 0) {
        int p = beg + slot;
        bool v = p < end;
        int pc = v ? p : beg;
        int src = srcs[pc];
        float evv = evf[4 * pc + head];
        const ushort_t* xp = xlb + (size_t)src * HID + c0;
        uint_t a0 = *(const uint_t*)(xp);
        uint_t a1 = *(const uint_t*)(xp + 2);
        uint_t a2 = *(const uint_t*)(xp + 4);
        for (int it = 0; it < cnt; ++it) {
            int pn = beg + (it + 1) * 4 + slot;
            bool vn = pn < end;
            int pcn = vn ? pn : beg;
            int srcn = srcs[pcn];
            float evn = evf[4 * pcn + head];
            const ushort_t* xpn = xlb + (size_t)srcn * HID + c0;
            uint_t b0 = *(const uint_t*)(xpn);
            uint_t b1 = *(const uint_t*)(xpn + 2);
            uint_t b2 = *(const uint_t*)(xpn + 4);

            float e = v ? evv : 0.f;
            n0 += e * bf2f((ushort_t)(a0 & 0xffff));
            n1 += e * bf2f((ushort_t)(a0 >> 16));
            n2 += e * bf2f((ushort_t)(a1 & 0xffff));
            n3 += e * bf2f((ushort_t)(a1 >> 16));
            n4 += e * bf2f((ushort_t)(a2 & 0xffff));
            n5 += e * bf2f((ushort_t)(a2 >> 16));
            den += e;

            v = vn; evv = evn; a0 = b0; a1 = b1; a2 = b2;
        }
    }
    n0 += __shfl_xor(n0, 16); n0 += __shfl_xor(n0, 32);
    n1 += __shfl_xor(n1, 16); n1 += __shfl_xor(n1, 32);
    n2 += __shfl_xor(n2, 16); n2 += __shfl_xor(n2, 32);
    n3 += __shfl_xor(n3, 16); n3 += __shfl_xor(n3, 32);
    n4 += __shfl_xor(n4, 16); n4 += __shfl_xor(n4, 32);
    n5 += __shfl_xor(n5, 16); n5 += __shfl_xor(n5, 32);
    den += __shfl_xor(den, 16); den += __shfl_xor(den, 32);

    size_t nb = (size_t)node * HID + c0;
    float inv = 1.f / (den + 1e-16f);
    float v0 = h[nb + 0] + n0 * inv + convb[c0 + 0];
    float v1 = h[nb + 1] + n1 * inv + convb[c0 + 1];
    float v2 = h[nb + 2] + n2 * inv + convb[c0 + 2];
    float v3 = h[nb + 3] + n3 * inv + convb[c0 + 3];
    float v4 = h[nb + 4] + n4 * inv + convb[c0 + 4];
    float v5 = h[nb + 5] + n5 * inv + convb[c0 + 5];
    float sm = v0 + v1 + v2 + v3 + v4 + v5;
    sm += __shfl_xor(sm, 1); sm += __shfl_xor(sm, 2);
    sm += __shfl_xor(sm, 4); sm += __shfl_xor(sm, 8);
    float mu = sm * (1.f / 96.f);
    float d0 = v0 - mu, d1 = v1 - mu, d2 = v2 - mu;
    float d3 = v3 - mu, d4 = v4 - mu, d5 = v5 - mu;
    float sv = d0 * d0 + d1 * d1 + d2 * d2 + d3 * d3 + d4 * d4 + d5 * d5;
    sv += __shfl_xor(sv, 1); sv += __shfl_xor(sv, 2);
    sv += __shfl_xor(sv, 4); sv += __shfl_xor(sv, 8);
    float rstd = rsqrtf(sv * (1.f / 96.f) + 1e-5f);
    if (slot == 0) {
        h[nb + 0] = d0 * rstd * lng[c0 + 0] + lnb[c0 + 0];
        h[nb + 1] = d1 * rstd * lng[c0 + 1] + lnb[c0 + 1];
        h[nb + 2] = d2 * rstd * lng[c0 + 2] + lnb[c0 + 2];
        h[nb + 3] = d3 * rstd * lng[c0 + 3] + lnb[c0 + 3];
        h[nb + 4] = d4 * rstd * lng[c0 + 4] + lnb[c0 + 4];
        h[nb + 5] = d5 * rstd * lng[c0 + 5] + lnb[c0 + 5];
    }
}

// ---- k_head_mfma: out = gelu(h@W1+b1)@W2+b2 via MFMA ----
// 64 nodes/block (4 waves x 16). W1^T bf16 in LDS (stride 104). Per wave:
// 3 A-frags from fp32 h; 3 n-tiles x 3 K-step MFMAs -> hidden[48] in D layout
// (col=lane&15 -> hidden unit, row=quad*4+r -> node); gelu + W2-dot in regs;
// 16-lane shuffle reduce; lane col==0 stores 4 nodes.
__global__ __launch_bounds__(256) void k_head_mfma(
    const float* __restrict__ h, const float* __restrict__ W1,
    const float* __restrict__ b1, const float* __restrict__ W2,
    const float* __restrict__ b2, float* __restrict__ out) {
    __shared__ ushort_t sW[48 * 104];
    __shared__ float sB1[48];
    __shared__ float sW2[48];
    int t = threadIdx.x;
    for (int idx = t; idx < 48 * 96; idx += 256) {
        int j = idx % 48, k = idx / 48;
        sW[j * 104 + k] = f2bf(W1[k * 48 + j]);
    }
    if (t < 48) { sB1[t] = b1[t]; sW2[t] = W2[t]; }
    __syncthreads();

    int wv = t >> 6, lane = t & 63;
    int m0 = blockIdx.x * 64 + wv * 16;
    if (m0 >= N_NODES) return;
    int col = lane & 15, quad = lane >> 4;

    bf16x8 afr[3];
    const float* hrow = h + (size_t)(m0 + col) * HID;
#pragma unroll
    for (int s = 0; s < 3; s++) {
        float4 v0 = *(const float4*)(hrow + s * 32 + quad * 8);
        float4 v1 = *(const float4*)(hrow + s * 32 + quad * 8 + 4);
        bf16x8 a;
        a[0] = (short)f2bf(v0.x); a[1] = (short)f2bf(v0.y);
        a[2] = (short)f2bf(v0.z); a[3] = (short)f2bf(v0.w);
        a[4] = (short)f2bf(v1.x); a[5] = (short)f2bf(v1.y);
        a[6] = (short)f2bf(v1.z); a[7] = (short)f2bf(v1.w);
        afr[s] = a;
    }

    const float inv_sqrt2 = 0.70710678118654752f;
    float y0 = 0.f, y1 = 0.f, y2 = 0.f, y3 = 0.f;
#pragma unroll
    for (int nt = 0; nt < 3; nt++) {
        f32x4 acc = {0.f, 0.f, 0.f, 0.f};
#pragma unroll
        for (int s = 0; s < 3; s++) {
            bf16x8 bfr = *(const bf16x8*)(sW + (nt * 16 + col) * 104 + s * 32 + quad * 8);
            acc = __builtin_amdgcn_mfma_f32_16x16x32_bf16(afr[s], bfr, acc, 0, 0, 0);
        }
        int ch = nt * 16 + col;
        float bias = sB1[ch], w2 = sW2[ch];
        float v, g;
        v = acc[0] + bias; g = 0.5f * v * (1.f + erff(v * inv_sqrt2)); y0 += g * w2;
        v = acc[1] + bias; g = 0.5f * v * (1.f + erff(v * inv_sqrt2)); y1 += g * w2;
        v = acc[2] + bias; g = 0.5f * v * (1.f + erff(v * inv_sqrt2)); y2 += g * w2;
        v = acc[3] + bias; g = 0.5f * v * (1.f + erff(v * inv_sqrt2)); y3 += g * w2;
    }
    y0 += __shfl_xor(y0, 1); y0 += __shfl_xor(y0, 2);
    y0 += __shfl_xor(y0, 4); y0 += __shfl_xor(y0, 8);
    y1 += __shfl_xor(y1, 1); y1 += __shfl_xor(y1, 2);
    y1 += __shfl_xor(y1, 4); y1 += __shfl_xor(y1, 8);
    y2 += __shfl_xor(y2, 1); y2 += __shfl_xor(y2, 2);
    y2 += __shfl_xor(y2, 4); y2 += __shfl_xor(y2, 8);
    y3 += __shfl_xor(y3, 1); y3 += __shfl_xor(y3, 2);
    y3 += __shfl_xor(y3, 4); y3 += __shfl_xor(y3, 8);
    if (col == 0) {
        float bb = b2[0];
        out[m0 + quad * 4 + 0] = y0 + bb;
        out[m0 + quad * 4 + 1] = y1 + bb;
        out[m0 + quad * 4 + 2] = y2 + bb;
        out[m0 + quad * 4 + 3] = y3 + bb;
    }
}

extern "C" void kernel_launch(void* const* d_in, const int* in_sizes, int n_in,
                              void* d_out, int out_size, void* d_ws, size_t ws_size,
                              hipStream_t stream) {
    const float* x       = (const float*)d_in[0];
    const int*   eidx    = (const int*)  d_in[1];
    const float* eattr   = (const float*)d_in[2];
    const float* proj_w  = (const float*)d_in[3];
    const float* proj_b  = (const float*)d_in[4];
    const float* lin_l_w = (const float*)d_in[5];
    const float* lin_l_b = (const float*)d_in[6];
    const float* lin_r_w = (const float*)d_in[7];
    const float* lin_r_b = (const float*)d_in[8];
    const float* lin_e_w = (const float*)d_in[9];
    const float* att     = (const float*)d_in[10];
    const float* conv_b  = (const float*)d_in[11];
    const float* ln_g    = (const float*)d_in[12];
    const float* ln_b    = (const float*)d_in[13];
    const float* head_w1 = (const float*)d_in[14];
    const float* head_b1 = (const float*)d_in[15];
    const float* head_w2 = (const float*)d_in[16];
    const float* head_b2 = (const float*)d_in[17];
    float* out = (float*)d_out;

    char* p = (char*)d_ws;
    auto alloc = [&](size_t bytes) -> char* {
        char* r = p;
        p += (bytes + 255) & ~size_t(255);
        return r;
    };
    float*    h      = (float*)alloc(sizeof(float) * (size_t)N_NODES * HID);
    ushort_t* xl     = (ushort_t*)alloc(2 * (size_t)N_NODES * HID);
    ushort_t* xr     = (ushort_t*)alloc(2 * (size_t)N_NODES * HID);
    int*      deg    = (int*)alloc(4 * (size_t)N_NODES);
    int*      fill   = (int*)alloc(4 * (size_t)N_NODES);
    int*      rowptr = (int*)alloc(4 * (size_t)(N_NODES + 1));
    int*      bsum   = (int*)alloc(4 * 256);
    int*      srcs   = (int*)alloc(4 * (size_t)N_EDGES);
    int*      eidxp  = (int*)alloc(4 * (size_t)N_EDGES);
    int*      pdst   = (int*)alloc(4 * (size_t)N_EDGES);
    ushort_t* ea_csr = (ushort_t*)alloc(2 * (size_t)N_EDGES * ED);
    float4*   ev     = (float4*)alloc(16 * (size_t)N_EDGES);

    const int* srcA = eidx;
    const int* dstA = eidx + N_EDGES;

    int ebl4 = (N_EDGES / 4 + 255) / 256;  // 782
    int nbl  = (N_NODES + 255) / 256;      // 196

    hipMemsetAsync(deg, 0, 4 * (size_t)N_NODES, stream);
    hipMemsetAsync(fill, 0, 4 * (size_t)N_NODES, stream);
    k_count_deg<<<ebl4, 256, 0, stream>>>(dstA, deg);
    k_scan_block<<<nbl, 256, 0, stream>>>(deg, rowptr, bsum);
    k_scan_bsum<<<1, 256, 0, stream>>>(bsum, nbl);
    k_scan_add<<<nbl, 256, 0, stream>>>(rowptr, bsum);
    k_scatter<<<ebl4, 256, 0, stream>>>(srcA, dstA, rowptr, fill, srcs, eidxp, pdst);
    k_perm<<<(N_EDGES * 4) / 256, 256, 0, stream>>>(eidxp, eattr, ea_csr);

    k_proj<<<N_NODES / 16, 192, 0, stream>>>(x, proj_w, proj_b, h);
    for (int l = 0; l < NLAYER; l++) {
        k_linlr_mfma<<<(N_NODES + 63) / 64, 256, 0, stream>>>(
            h, lin_l_w + (size_t)l * HID * HID, lin_l_b + (size_t)l * HID,
            lin_r_w + (size_t)l * HID * HID, lin_r_b + (size_t)l * HID, xl, xr);
        k_ev<<<1563, 256, 0, stream>>>(xl, xr, ea_csr, srcs, pdst,
                                       lin_e_w + (size_t)l * ED * HID,
                                       att + (size_t)l * HID,
                                       (float4*)ev);
        k_agg<<<N_NODES / 4, 256, 0, stream>>>(
            xl, (const float*)ev, srcs, rowptr, conv_b + (size_t)l * HID,
            ln_g + (size_t)l * HID, ln_b + (size_t)l * HID, h);
    }
    k_head_mfma<<<(N_NODES + 63) / 64, 256, 0, stream>>>(h, head_w1, head_b1,
                                                         head_w2, head_b2, out);
}

// Round 6
// 587.229 us; speedup vs baseline: 2.6683x; 1.0361x over previous
//
#include <hip/hip_runtime.h>

constexpr int N_NODES = 50000;
constexpr int N_EDGES = 800000;
constexpr int ND  = 32;
constexpr int ED  = 16;
constexpr int HID = 96;
constexpr int NLAYER = 3;

typedef unsigned short ushort_t;
typedef unsigned int uint_t;
typedef __attribute__((ext_vector_type(8))) short bf16x8;
typedef __attribute__((ext_vector_type(4))) float f32x4;

__device__ __forceinline__ float bf2f(ushort_t u) {
    union { float f; uint_t ui; } c; c.ui = ((uint_t)u) << 16; return c.f;
}
__device__ __forceinline__ ushort_t f2bf(float f) {
    uint_t u = __float_as_uint(f);
    return (ushort_t)((u + 0x7FFFu + ((u >> 16) & 1u)) >> 16);  // RNE
}

// ---------------- CSR build (by dst), once per call ----------------
__global__ void k_count_deg(const int* __restrict__ dst, int* __restrict__ deg) {
    int e4 = blockIdx.x * 256 + threadIdx.x;
    if (e4 * 4 >= N_EDGES) return;
    int4 d = ((const int4*)dst)[e4];
    atomicAdd(&deg[d.x], 1); atomicAdd(&deg[d.y], 1);
    atomicAdd(&deg[d.z], 1); atomicAdd(&deg[d.w], 1);
}

__global__ void k_scan_block(const int* __restrict__ deg, int* __restrict__ rowptr,
                             int* __restrict__ bsum) {
    __shared__ int s[256];
    int i = blockIdx.x * 256 + threadIdx.x;
    int v = (i < N_NODES) ? deg[i] : 0;
    s[threadIdx.x] = v;
    __syncthreads();
    for (int off = 1; off < 256; off <<= 1) {
        int t = (threadIdx.x >= off) ? s[threadIdx.x - off] : 0;
        __syncthreads();
        s[threadIdx.x] += t;
        __syncthreads();
    }
    if (i < N_NODES) rowptr[i] = s[threadIdx.x] - v;
    if (threadIdx.x == 255) bsum[blockIdx.x] = s[255];
}

__global__ void k_scan_bsum(int* __restrict__ bsum, int nb) {
    __shared__ int s[256];
    int t = threadIdx.x;
    int v = (t < nb) ? bsum[t] : 0;
    s[t] = v;
    __syncthreads();
    for (int off = 1; off < 256; off <<= 1) {
        int tv = (t >= off) ? s[t - off] : 0;
        __syncthreads();
        s[t] += tv;
        __syncthreads();
    }
    if (t < nb) bsum[t] = s[t] - v;
}

// also initializes the scatter cursor (fill = rowptr)
__global__ void k_scan_add(int* __restrict__ rowptr, const int* __restrict__ bsum,
                           int* __restrict__ fill) {
    int i = blockIdx.x * 256 + threadIdx.x;
    if (i < N_NODES) {
        int v = rowptr[i] + bsum[blockIdx.x];
        rowptr[i] = v;
        fill[i] = v;
    }
    if (i == 0) rowptr[N_NODES] = N_EDGES;
}

// ---- scatter + eattr permute fused: writes srcs/pdst + bf16 eattr in CSR order ----
__global__ void k_scatter(const int* __restrict__ src, const int* __restrict__ dst,
                          const float* __restrict__ eattr, int* __restrict__ fill,
                          int* __restrict__ srcs, int* __restrict__ pdst,
                          ushort_t* __restrict__ ea) {
    int e4 = blockIdx.x * 256 + threadIdx.x;
    if (e4 * 4 >= N_EDGES) return;
    int4 s = ((const int4*)src)[e4];
    int4 d = ((const int4*)dst)[e4];
    int e0 = e4 * 4;
    int sv[4] = {s.x, s.y, s.z, s.w};
    int dv[4] = {d.x, d.y, d.z, d.w};
#pragma unroll
    for (int j = 0; j < 4; j++) {
        int pos = atomicAdd(&fill[dv[j]], 1);
        srcs[pos] = sv[j];
        pdst[pos] = dv[j];
        const float4* er = (const float4*)(eattr + (size_t)(e0 + j) * ED);
        uint2* ew = (uint2*)(ea + (size_t)pos * ED);
#pragma unroll
        for (int q = 0; q < 4; q++) {
            float4 v = er[q];
            uint_t lo = (uint_t)f2bf(v.x) | ((uint_t)f2bf(v.y) << 16);
            uint_t hi = (uint_t)f2bf(v.z) | ((uint_t)f2bf(v.w) << 16);
            ew[q] = make_uint2(lo, hi);
        }
    }
}

// ---------------- proj: h = x @ proj_w + proj_b  (K=32) ----------------
__global__ __launch_bounds__(192) void k_proj(const float* __restrict__ x,
                                              const float* __restrict__ pw,
                                              const float* __restrict__ pb,
                                              float* __restrict__ h) {
    int t = threadIdx.x;
    int c = t % 96, half = t / 96;
    float wreg[ND];
#pragma unroll
    for (int k = 0; k < ND; k++) wreg[k] = pw[k * HID + c];
    float b = pb[c];
    int n0 = blockIdx.x * 16 + half * 8;
    for (int i = 0; i < 8; i += 2) {
        int na = n0 + i, nb = na + 1;
        const float4* xa = (const float4*)(x + (size_t)na * ND);
        const float4* xb = (const float4*)(x + (size_t)nb * ND);
        float accA = b, accB = b;
#pragma unroll
        for (int k4 = 0; k4 < ND / 4; k4++) {
            float4 va = xa[k4], vb = xb[k4];
            accA += va.x * wreg[4 * k4] + va.y * wreg[4 * k4 + 1] +
                    va.z * wreg[4 * k4 + 2] + va.w * wreg[4 * k4 + 3];
            accB += vb.x * wreg[4 * k4] + vb.y * wreg[4 * k4 + 1] +
                    vb.z * wreg[4 * k4 + 2] + vb.w * wreg[4 * k4 + 3];
        }
        h[(size_t)na * HID + c] = accA;
        h[(size_t)nb * HID + c] = accB;
    }
}

// ---- k_linlr_mfma: [xl|xr] = h @ [Wl|Wr] + [bl|br], bf16 out, MFMA ----
__global__ __launch_bounds__(256) void k_linlr_mfma(
    const float* __restrict__ h, const float* __restrict__ Wl,
    const float* __restrict__ bl, const float* __restrict__ Wr,
    const float* __restrict__ br, ushort_t* __restrict__ xl,
    ushort_t* __restrict__ xr) {
    __shared__ ushort_t sW[192 * 104];
    __shared__ float sB[192];
    int t = threadIdx.x;

    for (int idx = t; idx < 192 * 96; idx += 256) {
        int n = idx % 192, k = idx / 192;
        float v = (n < 96) ? Wl[k * 96 + n] : Wr[k * 96 + (n - 96)];
        sW[n * 104 + k] = f2bf(v);
    }
    if (t < 192) sB[t] = (t < 96) ? bl[t] : br[t - 96];
    __syncthreads();

    int wv = t >> 6, lane = t & 63;
    int m0 = blockIdx.x * 64 + wv * 16;
    if (m0 >= N_NODES) return;
    int m = lane & 15, quad = lane >> 4;

    bf16x8 afr[3];
    const float* hrow = h + (size_t)(m0 + m) * HID;
#pragma unroll
    for (int s = 0; s < 3; s++) {
        float4 v0 = *(const float4*)(hrow + s * 32 + quad * 8);
        float4 v1 = *(const float4*)(hrow + s * 32 + quad * 8 + 4);
        bf16x8 a;
        a[0] = (short)f2bf(v0.x); a[1] = (short)f2bf(v0.y);
        a[2] = (short)f2bf(v0.z); a[3] = (short)f2bf(v0.w);
        a[4] = (short)f2bf(v1.x); a[5] = (short)f2bf(v1.y);
        a[6] = (short)f2bf(v1.z); a[7] = (short)f2bf(v1.w);
        afr[s] = a;
    }

#pragma unroll
    for (int nt = 0; nt < 12; nt++) {
        int ch = nt * 16 + m;
        f32x4 acc = {0.f, 0.f, 0.f, 0.f};
#pragma unroll
        for (int s = 0; s < 3; s++) {
            bf16x8 bfr = *(const bf16x8*)(sW + (nt * 16 + m) * 104 + s * 32 + quad * 8);
            acc = __builtin_amdgcn_mfma_f32_16x16x32_bf16(afr[s], bfr, acc, 0, 0, 0);
        }
        float bias = sB[ch];
        ushort_t* dst = (ch < 96) ? (xl + (size_t)(m0 + quad * 4) * HID + ch)
                                  : (xr + (size_t)(m0 + quad * 4) * HID + (ch - 96));
#pragma unroll
        for (int r = 0; r < 4; r++)
            dst[(size_t)r * HID] = f2bf(acc[r] + bias);
    }
}

// ---- k_ev: edge-parallel attention weights via MFMA, 2-deep pipelined ----
// Wave = 128 consecutive CSR positions, 8 batches of 16. srcs/pdst preloaded
// as int2/lane, extracted per batch via shfl (no per-batch index load).
// Exact coverage: 6250 waves x 128 = 800000 -> no bounds checks in the loop.
__global__ __launch_bounds__(256) void k_ev(
    const ushort_t* __restrict__ xlb, const ushort_t* __restrict__ xrb,
    const ushort_t* __restrict__ ea, const int* __restrict__ srcs,
    const int* __restrict__ pdst, const float* __restrict__ WeL,
    const float* __restrict__ attL, float4* __restrict__ ev) {
    int wid = blockIdx.x * 4 + (threadIdx.x >> 6);
    int lane = threadIdx.x & 63;
    if (wid >= N_EDGES / 128) return;
    int col = lane & 15, quad = lane >> 4;
    int comp = col & 1, base = col >> 1;

    // preload this wave's 128 srcs/pdst values (2 per lane)
    int2 sp = *(const int2*)(srcs + wid * 128 + 2 * lane);
    int2 dp = *(const int2*)(pdst + wid * 128 + 2 * lane);

    // wave-invariant A fragments (We^T) and att values
    bf16x8 afr[6];
#pragma unroll
    for (int mc = 0; mc < 6; mc++) {
        bf16x8 a = {0, 0, 0, 0, 0, 0, 0, 0};
        if (quad < 2) {
#pragma unroll
            for (int j = 0; j < 8; j++)
                a[j] = (short)f2bf(WeL[(quad * 8 + j) * HID + mc * 16 + col]);
        }
        afr[mc] = a;
    }
    float attr[6][4];
#pragma unroll
    for (int mc = 0; mc < 6; mc++)
#pragma unroll
        for (int r = 0; r < 4; r++)
            attr[mc][r] = attL[mc * 16 + quad * 4 + r];

    // pipeline registers (2 batches in flight)
    bf16x8 bfr[2];
    uint2 xu[2][6], ru[2][6];

    auto getsd = [&](int b, int& sv, int& dv) {
        int sl = b * 8 + base;
        int sx = __shfl(sp.x, sl), sy = __shfl(sp.y, sl);
        int dx = __shfl(dp.x, sl), dy = __shfl(dp.y, sl);
        sv = comp ? sy : sx;
        dv = comp ? dy : dx;
    };
    auto issue = [&](int b, int pp) {
        int sv, dv;
        getsd(b, sv, dv);
        int p = wid * 128 + b * 16 + col;
        bf16x8 z8 = {0, 0, 0, 0, 0, 0, 0, 0};
        bfr[pp] = (quad < 2) ? *(const bf16x8*)(ea + (size_t)p * ED + quad * 8) : z8;
        const ushort_t* xp = xlb + (size_t)sv * HID + quad * 4;
        const ushort_t* rp = xrb + (size_t)dv * HID + quad * 4;
#pragma unroll
        for (int mc = 0; mc < 6; mc++) {
            xu[pp][mc] = *(const uint2*)(xp + mc * 16);
            ru[pp][mc] = *(const uint2*)(rp + mc * 16);
        }
    };

    issue(0, 0);
#pragma unroll
    for (int b = 0; b < 8; b++) {
        int pp = b & 1;
        if (b < 7) issue(b + 1, pp ^ 1);

        f32x4 zero4 = {0.f, 0.f, 0.f, 0.f};
        f32x4 d[6];
#pragma unroll
        for (int mc = 0; mc < 6; mc++)
            d[mc] = __builtin_amdgcn_mfma_f32_16x16x32_bf16(afr[mc], bfr[pp], zero4, 0, 0, 0);

        float s[6];
#pragma unroll
        for (int mc = 0; mc < 6; mc++) {
            uint2 a = xu[pp][mc], r = ru[pp][mc];
            float x0 = bf2f((ushort_t)(a.x & 0xffff)), x1 = bf2f((ushort_t)(a.x >> 16));
            float x2 = bf2f((ushort_t)(a.y & 0xffff)), x3 = bf2f((ushort_t)(a.y >> 16));
            float r0 = bf2f((ushort_t)(r.x & 0xffff)), r1 = bf2f((ushort_t)(r.x >> 16));
            float r2 = bf2f((ushort_t)(r.y & 0xffff)), r3 = bf2f((ushort_t)(r.y >> 16));
            float z0 = x0 + r0 + d[mc][0]; z0 = z0 > 0.f ? z0 : 0.2f * z0;
            float z1 = x1 + r1 + d[mc][1]; z1 = z1 > 0.f ? z1 : 0.2f * z1;
            float z2 = x2 + r2 + d[mc][2]; z2 = z2 > 0.f ? z2 : 0.2f * z2;
            float z3 = x3 + r3 + d[mc][3]; z3 = z3 > 0.f ? z3 : 0.2f * z3;
            s[mc] = z0 * attr[mc][0] + z1 * attr[mc][1] +
                    z2 * attr[mc][2] + z3 * attr[mc][3];
        }
        float U[6], V[6];
#pragma unroll
        for (int mc = 0; mc < 6; mc++) {
            U[mc] = s[mc] + __shfl_xor(s[mc], 16);
            V[mc] = U[mc] + __shfl_xor(U[mc], 32);
        }
        if (quad == 0) {
            float h0 = V[0] + U[1];
            float h1 = (V[1] - U[1]) + V[2];
            float h2 = V[3] + U[4];
            float h3 = (V[4] - U[4]) + V[5];
            int p = wid * 128 + b * 16 + col;
            ev[p] = make_float4(__expf(h0), __expf(h1), __expf(h2), __expf(h3));
        }
    }
}

// ---- k_agg: weighted sum + residual + LayerNorm ----
__global__ __launch_bounds__(256) void k_agg(
    const ushort_t* __restrict__ xlb, const float* __restrict__ evf,
    const int* __restrict__ srcs, const int* __restrict__ rowptr,
    const float* __restrict__ convb, const float* __restrict__ lng,
    const float* __restrict__ lnb, float* __restrict__ h) {
    int lane = threadIdx.x & 63;
    int node = blockIdx.x * 4 + (threadIdx.x >> 6);
    int slot = lane >> 4, q = lane & 15;
    int c0 = q * 6, head = q >> 2;
    int beg = rowptr[node], end = rowptr[node + 1];
    int cnt = (end - beg + 3) >> 2;

    float n0 = 0.f, n1 = 0.f, n2 = 0.f, n3 = 0.f, n4 = 0.f, n5 = 0.f, den = 0.f;
    if (cnt > 0) {
        int p = beg + slot;
        bool v = p < end;
        int pc = v ? p : beg;
        int src = srcs[pc];
        float evv = evf[4 * pc + head];
        const ushort_t* xp = xlb + (size_t)src * HID + c0;
        uint_t a0 = *(const uint_t*)(xp);
        uint_t a1 = *(const uint_t*)(xp + 2);
        uint_t a2 = *(const uint_t*)(xp + 4);
        for (int it = 0; it < cnt; ++it) {
            int pn = beg + (it + 1) * 4 + slot;
            bool vn = pn < end;
            int pcn = vn ? pn : beg;
            int srcn = srcs[pcn];
            float evn = evf[4 * pcn + head];
            const ushort_t* xpn = xlb + (size_t)srcn * HID + c0;
            uint_t b0 = *(const uint_t*)(xpn);
            uint_t b1 = *(const uint_t*)(xpn + 2);
            uint_t b2 = *(const uint_t*)(xpn + 4);

            float e = v ? evv : 0.f;
            n0 += e * bf2f((ushort_t)(a0 & 0xffff));
            n1 += e * bf2f((ushort_t)(a0 >> 16));
            n2 += e * bf2f((ushort_t)(a1 & 0xffff));
            n3 += e * bf2f((ushort_t)(a1 >> 16));
            n4 += e * bf2f((ushort_t)(a2 & 0xffff));
            n5 += e * bf2f((ushort_t)(a2 >> 16));
            den += e;

            v = vn; evv = evn; a0 = b0; a1 = b1; a2 = b2;
        }
    }
    n0 += __shfl_xor(n0, 16); n0 += __shfl_xor(n0, 32);
    n1 += __shfl_xor(n1, 16); n1 += __shfl_xor(n1, 32);
    n2 += __shfl_xor(n2, 16); n2 += __shfl_xor(n2, 32);
    n3 += __shfl_xor(n3, 16); n3 += __shfl_xor(n3, 32);
    n4 += __shfl_xor(n4, 16); n4 += __shfl_xor(n4, 32);
    n5 += __shfl_xor(n5, 16); n5 += __shfl_xor(n5, 32);
    den += __shfl_xor(den, 16); den += __shfl_xor(den, 32);

    size_t nb = (size_t)node * HID + c0;
    float inv = 1.f / (den + 1e-16f);
    float v0 = h[nb + 0] + n0 * inv + convb[c0 + 0];
    float v1 = h[nb + 1] + n1 * inv + convb[c0 + 1];
    float v2 = h[nb + 2] + n2 * inv + convb[c0 + 2];
    float v3 = h[nb + 3] + n3 * inv + convb[c0 + 3];
    float v4 = h[nb + 4] + n4 * inv + convb[c0 + 4];
    float v5 = h[nb + 5] + n5 * inv + convb[c0 + 5];
    float sm = v0 + v1 + v2 + v3 + v4 + v5;
    sm += __shfl_xor(sm, 1); sm += __shfl_xor(sm, 2);
    sm += __shfl_xor(sm, 4); sm += __shfl_xor(sm, 8);
    float mu = sm * (1.f / 96.f);
    float d0 = v0 - mu, d1 = v1 - mu, d2 = v2 - mu;
    float d3 = v3 - mu, d4 = v4 - mu, d5 = v5 - mu;
    float sv = d0 * d0 + d1 * d1 + d2 * d2 + d3 * d3 + d4 * d4 + d5 * d5;
    sv += __shfl_xor(sv, 1); sv += __shfl_xor(sv, 2);
    sv += __shfl_xor(sv, 4); sv += __shfl_xor(sv, 8);
    float rstd = rsqrtf(sv * (1.f / 96.f) + 1e-5f);
    if (slot == 0) {
        h[nb + 0] = d0 * rstd * lng[c0 + 0] + lnb[c0 + 0];
        h[nb + 1] = d1 * rstd * lng[c0 + 1] + lnb[c0 + 1];
        h[nb + 2] = d2 * rstd * lng[c0 + 2] + lnb[c0 + 2];
        h[nb + 3] = d3 * rstd * lng[c0 + 3] + lnb[c0 + 3];
        h[nb + 4] = d4 * rstd * lng[c0 + 4] + lnb[c0 + 4];
        h[nb + 5] = d5 * rstd * lng[c0 + 5] + lnb[c0 + 5];
    }
}

// ---- k_head_mfma: out = gelu(h@W1+b1)@W2+b2 via MFMA ----
__global__ __launch_bounds__(256) void k_head_mfma(
    const float* __restrict__ h, const float* __restrict__ W1,
    const float* __restrict__ b1, const float* __restrict__ W2,
    const float* __restrict__ b2, float* __restrict__ out) {
    __shared__ ushort_t sW[48 * 104];
    __shared__ float sB1[48];
    __shared__ float sW2[48];
    int t = threadIdx.x;
    for (int idx = t; idx < 48 * 96; idx += 256) {
        int j = idx % 48, k = idx / 48;
        sW[j * 104 + k] = f2bf(W1[k * 48 + j]);
    }
    if (t < 48) { sB1[t] = b1[t]; sW2[t] = W2[t]; }
    __syncthreads();

    int wv = t >> 6, lane = t & 63;
    int m0 = blockIdx.x * 64 + wv * 16;
    if (m0 >= N_NODES) return;
    int col = lane & 15, quad = lane >> 4;

    bf16x8 afr[3];
    const float* hrow = h + (size_t)(m0 + col) * HID;
#pragma unroll
    for (int s = 0; s < 3; s++) {
        float4 v0 = *(const float4*)(hrow + s * 32 + quad * 8);
        float4 v1 = *(const float4*)(hrow + s * 32 + quad * 8 + 4);
        bf16x8 a;
        a[0] = (short)f2bf(v0.x); a[1] = (short)f2bf(v0.y);
        a[2] = (short)f2bf(v0.z); a[3] = (short)f2bf(v0.w);
        a[4] = (short)f2bf(v1.x); a[5] = (short)f2bf(v1.y);
        a[6] = (short)f2bf(v1.z); a[7] = (short)f2bf(v1.w);
        afr[s] = a;
    }

    const float inv_sqrt2 = 0.70710678118654752f;
    float y0 = 0.f, y1 = 0.f, y2 = 0.f, y3 = 0.f;
#pragma unroll
    for (int nt = 0; nt < 3; nt++) {
        f32x4 acc = {0.f, 0.f, 0.f, 0.f};
#pragma unroll
        for (int s = 0; s < 3; s++) {
            bf16x8 bfr = *(const bf16x8*)(sW + (nt * 16 + col) * 104 + s * 32 + quad * 8);
            acc = __builtin_amdgcn_mfma_f32_16x16x32_bf16(afr[s], bfr, acc, 0, 0, 0);
        }
        int ch = nt * 16 + col;
        float bias = sB1[ch], w2 = sW2[ch];
        float v, g;
        v = acc[0] + bias; g = 0.5f * v * (1.f + erff(v * inv_sqrt2)); y0 += g * w2;
        v = acc[1] + bias; g = 0.5f * v * (1.f + erff(v * inv_sqrt2)); y1 += g * w2;
        v = acc[2] + bias; g = 0.5f * v * (1.f + erff(v * inv_sqrt2)); y2 += g * w2;
        v = acc[3] + bias; g = 0.5f * v * (1.f + erff(v * inv_sqrt2)); y3 += g * w2;
    }
    y0 += __shfl_xor(y0, 1); y0 += __shfl_xor(y0, 2);
    y0 += __shfl_xor(y0, 4); y0 += __shfl_xor(y0, 8);
    y1 += __shfl_xor(y1, 1); y1 += __shfl_xor(y1, 2);
    y1 += __shfl_xor(y1, 4); y1 += __shfl_xor(y1, 8);
    y2 += __shfl_xor(y2, 1); y2 += __shfl_xor(y2, 2);
    y2 += __shfl_xor(y2, 4); y2 += __shfl_xor(y2, 8);
    y3 += __shfl_xor(y3, 1); y3 += __shfl_xor(y3, 2);
    y3 += __shfl_xor(y3, 4); y3 += __shfl_xor(y3, 8);
    if (col == 0) {
        float bb = b2[0];
        out[m0 + quad * 4 + 0] = y0 + bb;
        out[m0 + quad * 4 + 1] = y1 + bb;
        out[m0 + quad * 4 + 2] = y2 + bb;
        out[m0 + quad * 4 + 3] = y3 + bb;
    }
}

extern "C" void kernel_launch(void* const* d_in, const int* in_sizes, int n_in,
                              void* d_out, int out_size, void* d_ws, size_t ws_size,
                              hipStream_t stream) {
    const float* x       = (const float*)d_in[0];
    const int*   eidx    = (const int*)  d_in[1];
    const float* eattr   = (const float*)d_in[2];
    const float* proj_w  = (const float*)d_in[3];
    const float* proj_b  = (const float*)d_in[4];
    const float* lin_l_w = (const float*)d_in[5];
    const float* lin_l_b = (const float*)d_in[6];
    const float* lin_r_w = (const float*)d_in[7];
    const float* lin_r_b = (const float*)d_in[8];
    const float* lin_e_w = (const float*)d_in[9];
    const float* att     = (const float*)d_in[10];
    const float* conv_b  = (const float*)d_in[11];
    const float* ln_g    = (const float*)d_in[12];
    const float* ln_b    = (const float*)d_in[13];
    const float* head_w1 = (const float*)d_in[14];
    const float* head_b1 = (const float*)d_in[15];
    const float* head_w2 = (const float*)d_in[16];
    const float* head_b2 = (const float*)d_in[17];
    float* out = (float*)d_out;

    char* p = (char*)d_ws;
    auto alloc = [&](size_t bytes) -> char* {
        char* r = p;
        p += (bytes + 255) & ~size_t(255);
        return r;
    };
    float*    h      = (float*)alloc(sizeof(float) * (size_t)N_NODES * HID);
    ushort_t* xl     = (ushort_t*)alloc(2 * (size_t)N_NODES * HID);
    ushort_t* xr     = (ushort_t*)alloc(2 * (size_t)N_NODES * HID);
    int*      deg    = (int*)alloc(4 * (size_t)N_NODES);
    int*      fill   = (int*)alloc(4 * (size_t)N_NODES);
    int*      rowptr = (int*)alloc(4 * (size_t)(N_NODES + 1));
    int*      bsum   = (int*)alloc(4 * 256);
    int*      srcs   = (int*)alloc(4 * ((size_t)N_EDGES + 256));  // padded: int2 preload
    int*      pdst   = (int*)alloc(4 * ((size_t)N_EDGES + 256));
    ushort_t* ea_csr = (ushort_t*)alloc(2 * (size_t)N_EDGES * ED);
    float4*   ev     = (float4*)alloc(16 * (size_t)N_EDGES);

    const int* srcA = eidx;
    const int* dstA = eidx + N_EDGES;

    int ebl4 = (N_EDGES / 4 + 255) / 256;  // 782
    int nbl  = (N_NODES + 255) / 256;      // 196

    hipMemsetAsync(deg, 0, 4 * (size_t)N_NODES, stream);
    k_count_deg<<<ebl4, 256, 0, stream>>>(dstA, deg);
    k_scan_block<<<nbl, 256, 0, stream>>>(deg, rowptr, bsum);
    k_scan_bsum<<<1, 256, 0, stream>>>(bsum, nbl);
    k_scan_add<<<nbl, 256, 0, stream>>>(rowptr, bsum, fill);
    k_scatter<<<ebl4, 256, 0, stream>>>(srcA, dstA, eattr, fill, srcs, pdst, ea_csr);

    k_proj<<<N_NODES / 16, 192, 0, stream>>>(x, proj_w, proj_b, h);
    for (int l = 0; l < NLAYER; l++) {
        k_linlr_mfma<<<(N_NODES + 63) / 64, 256, 0, stream>>>(
            h, lin_l_w + (size_t)l * HID * HID, lin_l_b + (size_t)l * HID,
            lin_r_w + (size_t)l * HID * HID, lin_r_b + (size_t)l * HID, xl, xr);
        k_ev<<<1563, 256, 0, stream>>>(xl, xr, ea_csr, srcs, pdst,
                                       lin_e_w + (size_t)l * ED * HID,
                                       att + (size_t)l * HID,
                                       (float4*)ev);
        k_agg<<<N_NODES / 4, 256, 0, stream>>>(
            xl, (const float*)ev, srcs, rowptr, conv_b + (size_t)l * HID,
            ln_g + (size_t)l * HID, ln_b + (size_t)l * HID, h);
    }
    k_head_mfma<<<(N_NODES + 63) / 64, 256, 0, stream>>>(h, head_w1, head_b1,
                                                         head_w2, head_b2, out);
}